// Round 4
// baseline (532.802 us; speedup 1.0000x reference)
//
#include <hip/hip_runtime.h>
#include <hip/hip_bf16.h>
#include <stdint.h>

typedef unsigned short u16;
typedef __attribute__((ext_vector_type(8))) short short8;
typedef __attribute__((ext_vector_type(4))) short short4v;
typedef __attribute__((ext_vector_type(4))) float f32x4;

__device__ __forceinline__ float bf2f(u16 b){ union {unsigned u; float f;} v; v.u = ((unsigned)b)<<16; return v.f; }
__device__ __forceinline__ u16 f2bf(float f){ union {unsigned u; float f;} v; v.f = f; unsigned r = v.u + 0x7FFF + ((v.u>>16)&1); return (u16)(r>>16); }

// ---------------- adaptive adjacency
__global__ __launch_bounds__(256) void k_adp(const float* __restrict__ nv1, const float* __restrict__ nv2,
                                             float* __restrict__ adp){
  int row = blockIdx.x; int j = threadIdx.x;
  float s = 0.f;
  #pragma unroll
  for(int k=0;k<10;k++) s = fmaf(nv1[row*10+k], nv2[k*256+j], s);
  s = s > 0.f ? s : 0.f;
  float val = (s == 0.f) ? -1e10f : s;
  __shared__ float red[256];
  red[j] = val; __syncthreads();
  for(int off=128; off>0; off>>=1){ if(j<off) red[j] = fmaxf(red[j], red[j+off]); __syncthreads(); }
  float mx = red[0]; __syncthreads();
  float e = __expf(val - mx);
  red[j] = e; __syncthreads();
  for(int off=128; off>0; off>>=1){ if(j<off) red[j] += red[j+off]; __syncthreads(); }
  adp[row*256+j] = e / red[0];
}

// ---------------- badj[s][w][v] = src_s[v][w]
__global__ __launch_bounds__(256) void k_badj(const float* __restrict__ s0, const float* __restrict__ s1,
                                              const float* __restrict__ adp, u16* __restrict__ badj){
  int s = blockIdx.x >> 8; int w = blockIdx.x & 255; int v = threadIdx.x;
  const float* src = s==0 ? s0 : (s==1 ? s1 : adp);
  badj[(s<<16) + (w<<8) + v] = f2bf(src[v*256 + w]);
}

// ---------------- weight prep
__global__ __launch_bounds__(256) void k_wprep(const float* __restrict__ wm1, const float* __restrict__ wm2,
                                               const float* __restrict__ wf1, const float* __restrict__ wg1,
                                               const float* __restrict__ wf2, const float* __restrict__ wg2,
                                               u16* __restrict__ whi, u16* __restrict__ wlo,
                                               u16* __restrict__ wcp){
  int idx = blockIdx.x*256 + threadIdx.x;
  if(idx < 14336){
    float w = (idx < 7168) ? wm1[idx] : wm2[idx-7168];
    u16 hh = f2bf(w);
    whi[idx] = hh;
    wlo[idx] = f2bf(w - bf2f(hh));
  } else {
    int e = idx - 14336;
    int blk = e >> 12; int rem = e & 4095;
    int row = rem >> 6; int kk = rem & 63;
    int tap = kk >> 5; int i = kk & 31; int o = row & 31;
    const float* wsrc = blk ? (row<32 ? wf2 : wg2) : (row<32 ? wf1 : wg1);
    float w = wsrc[(o*32+i)*2 + tap];
    u16 hh = f2bf(w);
    wcp[blk*8192 + 0    + rem] = hh;
    wcp[blk*8192 + 4096 + rem] = f2bf(w - bf2f(hh));
  }
}

// ---------------- x [b][c][n][t] f32 -> xT [b][t][c][n] bf16
__global__ __launch_bounds__(256) void k_tin(const float* __restrict__ x, u16* __restrict__ xT){
  int tile = blockIdx.x & 15; int slice = blockIdx.x >> 4;
  int b = slice >> 5, c = slice & 31;
  int tn0 = (tile & 3) * 64;
  int tt0 = (tile >> 2) * 64;
  const float* src = x + (size_t)slice*65536;
  __shared__ float l[64][65];
  int cc = threadIdx.x & 63, r0 = threadIdx.x >> 6;
  #pragma unroll
  for(int k=0;k<16;k++){ int r = r0 + 4*k;
    l[r][cc] = src[(size_t)(tn0 + r)*256 + tt0 + cc];
  }
  __syncthreads();
  #pragma unroll
  for(int k=0;k<16;k++){ int r = r0 + 4*k;
    xT[(((size_t)b*256 + (tt0+r))*32 + c)*256 + tn0 + cc] = f2bf(l[cc][r]);
  }
}

// ---------------- badj2[s] = badj[s] . badj[s]  (= (A^2)^T stored [w][v])
__global__ __launch_bounds__(256) void k_asq(const u16* __restrict__ badj,
                                             const float* __restrict__ s0, const float* __restrict__ s1,
                                             const float* __restrict__ adp, u16* __restrict__ badj2){
  __shared__ __align__(16) u16 lds[16384];
  int tid = threadIdx.x, bid = blockIdx.x;
  int s = bid >> 2, rt = bid & 3;
  int w0 = rt << 6;
  const u16* T = badj + (s<<16);
  const float* S = s==0 ? s0 : (s==1 ? s1 : adp);
  #pragma unroll
  for(int i=0;i<8;i++){
    int off = i*4096 + tid*16;
    int row = off >> 9;
    int P = (off >> 4) & 31;
    int L = (P & 16) | ((P & 15) ^ (row & 15));
    short8 v = *(const short8*)((const char*)T + (size_t)(w0 + row)*512 + L*16);
    *(short8*)((char*)lds + off) = v;
  }
  __syncthreads();
  int lane = tid & 63, wave = tid >> 6;
  int wr = (wave >> 1) << 5, wc = (wave & 1) << 7;
  f32x4 acc[2][8];
  #pragma unroll
  for(int a=0;a<2;a++)
    #pragma unroll
    for(int q=0;q<8;q++) acc[a][q] = {0.f,0.f,0.f,0.f};
  for(int ks=0; ks<8; ks++){
    short8 afr[2], bfr[8];
    #pragma unroll
    for(int mf=0; mf<2; mf++){
      int row = wr + mf*16 + (lane & 15);
      int L = ks*4 + (lane >> 4);
      int P = (L & 16) | ((L & 15) ^ (row & 15));
      afr[mf] = *(const short8*)&lds[row*256 + P*8];
    }
    #pragma unroll
    for(int nf=0; nf<8; nf++){
      int col = wc + nf*16 + (lane & 15);
      const float* src = S + (size_t)col*256 + ks*32 + (lane>>4)*8;
      #pragma unroll
      for(int jj=0;jj<8;jj++) bfr[nf][jj] = (short)f2bf(src[jj]);
    }
    #pragma unroll
    for(int mf=0;mf<2;mf++)
      #pragma unroll
      for(int nf=0;nf<8;nf++)
        acc[mf][nf] = __builtin_amdgcn_mfma_f32_16x16x32_bf16(afr[mf], bfr[nf], acc[mf][nf], 0,0,0);
  }
  u16* D = badj2 + (s<<16) + (size_t)w0*256;
  #pragma unroll
  for(int mf=0;mf<2;mf++)
    #pragma unroll
    for(int nf=0;nf<8;nf++)
      #pragma unroll
      for(int rr=0;rr<4;rr++){
        int row = wr + mf*16 + (lane>>4)*4 + rr;
        int col = wc + nf*16 + (lane&15);
        D[row*256 + col] = f2bf(acc[mf][nf][rr]);
      }
}

// ---------------- MFMA gated conv (+bias, sigmoid gate)
template<int HILO>
__global__ __launch_bounds__(256) void k_cv(const u16* __restrict__ X0, const u16* __restrict__ X1,
                                            const u16* __restrict__ wcp, int blk, int dil,
                                            const float* __restrict__ bfv, const float* __restrict__ bgv,
                                            u16* __restrict__ outh){
  __shared__ __align__(16) u16 pl[(1+HILO)*2*8192];
  const int NPART = 1+HILO;
  int tid = threadIdx.x, bid = blockIdx.x;
  int b = bid >> 8, t = bid & 255;
  size_t base_cur = ((size_t)(b*256 + t))*8192;
  const u16* Xs[2] = {X0, X1};
  #pragma unroll
  for(int part=0; part<NPART; part++){
    #pragma unroll
    for(int tap=0; tap<2; tap++){
      bool valid = (tap==1) || (t >= dil);
      const u16* src = Xs[part] + base_cur - (tap==0 ? (size_t)dil*8192 : 0);
      char* pb = (char*)pl + (tap*NPART + part)*16384;
      #pragma unroll
      for(int it=0; it<4; it++){
        int off = it*4096 + tid*16;
        int c = off >> 9;
        int byte = off & 511;
        short8 v = {0,0,0,0,0,0,0,0};
        if(valid) v = *(const short8*)(src + (off>>1));
        *(short8*)(pb + c*512 + (byte ^ ((c&24)<<2))) = v;
      }
    }
  }
  int lane = tid & 63, wave = tid >> 6;
  const u16* wb = wcp + blk*8192;
  short8 wfr[4][2][2];
  #pragma unroll
  for(int ot=0;ot<4;ot++)
    #pragma unroll
    for(int ks=0;ks<2;ks++)
      #pragma unroll
      for(int p=0;p<2;p++)
        wfr[ot][ks][p] = *(const short8*)(wb + p*4096 + (ot*16 + (lane&15))*64 + ks*32 + (lane>>4)*8);
  __syncthreads();

  f32x4 acc[4][4];
  #pragma unroll
  for(int a=0;a<4;a++)
    #pragma unroll
    for(int q=0;q<4;q++) acc[a][q] = {0.f,0.f,0.f,0.f};
  int nbase = wave << 6;
  #pragma unroll
  for(int nf=0; nf<4; nf++){
    int n = nbase + nf*16 + (lane & 15);
    #pragma unroll
    for(int ks=0; ks<2; ks++){
      short8 xv[NPART];
      #pragma unroll
      for(int p=0;p<NPART;p++){
        char* pb = (char*)pl + (ks*NPART + p)*16384;
        short8 v;
        #pragma unroll
        for(int jj=0;jj<8;jj++){
          int c = ((lane>>4)<<3) + jj;
          v[jj] = *(const short*)(pb + c*512 + ((n*2) ^ ((c&24)<<2)));
        }
        xv[p] = v;
      }
      #pragma unroll
      for(int ot=0; ot<4; ot++){
        acc[ot][nf] = __builtin_amdgcn_mfma_f32_16x16x32_bf16(wfr[ot][ks][0], xv[0], acc[ot][nf], 0,0,0);
        acc[ot][nf] = __builtin_amdgcn_mfma_f32_16x16x32_bf16(wfr[ot][ks][1], xv[0], acc[ot][nf], 0,0,0);
        if(HILO)
          acc[ot][nf] = __builtin_amdgcn_mfma_f32_16x16x32_bf16(wfr[ot][ks][0], xv[HILO], acc[ot][nf], 0,0,0);
      }
    }
  }
  u16* ob = outh + base_cur;
  #pragma unroll
  for(int ot=0; ot<2; ot++)
    #pragma unroll
    for(int nf=0; nf<4; nf++)
      #pragma unroll
      for(int rr=0; rr<4; rr++){
        int o = ot*16 + (lane>>4)*4 + rr;
        int n = nbase + nf*16 + (lane&15);
        float fv = acc[ot][nf][rr] + bfv[o];
        float gv = acc[ot+2][nf][rr] + bgv[o];
        ob[(size_t)o*256 + n] = f2bf(fv / (1.f + __expf(-gv)));
      }
}

// ---------------- hop GEMMs v2: 32-row x 128-col block tile, support+colhalf split grid,
// 2 GEMMs (A_s, A_s^2) per block sharing one staged A-tile; explicit 2-deep B prefetch;
// LDS reused for coalesced epilogue.  grid = nsup*2048; support = s_base + (bid>>11).
__global__ __launch_bounds__(256, 4) void k_hop(const u16* __restrict__ X,
                                                u16* y0, u16* y1, u16* y2, u16* y3, u16* y4, u16* y5,
                                                const u16* __restrict__ badj, const u16* __restrict__ badj2,
                                                int s_base){
  __shared__ __align__(16) u16 lA[8192];   // 16 KB: A-tile [32 rows][32 slots x 16B], then epi tile
  int tid = threadIdx.x, bid = blockIdx.x;
  int p = bid >> 11;                 // support slot within grid
  int r = bid & 2047;
  int b = r >> 9;
  int q = r & 511;
  int rb = q >> 1;                   // row tile 0..255
  int ch = q & 1;                    // col half
  int m0 = rb << 5, wc0 = ch << 7;
  int s = s_base + p;
  const u16* Xb = X + ((size_t)b << 21);

  // stage A-tile (32 rows x 256 v, row-XOR-swizzled via pre-swizzled global source)
  #pragma unroll
  for(int i=0;i<4;i++){
    int off = i*4096 + tid*16;
    int row = off >> 9;
    int P = (off >> 4) & 31;
    int L = (P & 16) | ((P & 15) ^ (row & 15));
    short8 v = *(const short8*)((const char*)Xb + (size_t)(m0 + row)*512 + L*16);
    *(short8*)((char*)lA + off) = v;
  }
  __syncthreads();

  int lane = tid & 63, wave = tid >> 6;
  int wr = (wave >> 1) << 4;           // 0/16
  int wc = wc0 + ((wave & 1) << 6);    // global col base of this wave (64 cols)

  // hoist A fragments: 8 ks x 1 row-tile
  short8 af[8];
  #pragma unroll
  for(int ks=0;ks<8;ks++){
    int row = wr + (lane & 15);
    int L = ks*4 + (lane >> 4);
    int P = (L & 16) | ((L & 15) ^ (row & 15));
    af[ks] = *(const short8*)&lA[row*256 + P*8];
  }

  u16* ys[6] = {y0,y1,y2,y3,y4,y5};
  #pragma unroll
  for(int j=0;j<2;j++){
    const u16* Aj = (j ? badj2 : badj) + ((size_t)s << 16);
    f32x4 acc[4];
    #pragma unroll
    for(int nf=0;nf<4;nf++) acc[nf] = {0.f,0.f,0.f,0.f};

    auto loadB = [&](short8* dst, int ksv){
      #pragma unroll
      for(int nf=0;nf<4;nf++)
        dst[nf] = *(const short8*)(Aj + (size_t)(wc + nf*16 + (lane&15))*256 + ksv*32 + (lane>>4)*8);
    };
    auto mfma4 = [&](const short8* buf, int ksv){
      #pragma unroll
      for(int nf=0;nf<4;nf++)
        acc[nf] = __builtin_amdgcn_mfma_f32_16x16x32_bf16(af[ksv], buf[nf], acc[nf], 0,0,0);
    };

    short8 e0[4], e1[4];
    loadB(e0, 0); loadB(e1, 1);
    mfma4(e0, 0); loadB(e0, 2);
    mfma4(e1, 1); loadB(e1, 3);
    mfma4(e0, 2); loadB(e0, 4);
    mfma4(e1, 3); loadB(e1, 5);
    mfma4(e0, 4); loadB(e0, 6);
    mfma4(e1, 5); loadB(e1, 7);
    mfma4(e0, 6);
    mfma4(e1, 7);

    // epilogue: stage 32x128 bf16 tile in lA (slot-XOR swizzle), then coalesced stores
    __syncthreads();   // af-hoist reads (j=0) / previous epi reads (j=1) complete
    #pragma unroll
    for(int nf=0;nf<4;nf++)
      #pragma unroll
      for(int rr=0;rr<4;rr++){
        int row = wr + (lane>>4)*4 + rr;
        int colb = ((wave&1)<<6) + nf*16 + (lane&15);
        int byte = colb*2;
        int L = byte >> 4;
        int P = L ^ (row & 15);
        *(u16*)((char*)lA + (row<<8) + (P<<4) + (byte&15)) = f2bf(acc[nf][rr]);
      }
    __syncthreads();
    const u16* Yb = ys[2*p + j] + ((size_t)b<<21) + (size_t)m0*256;
    #pragma unroll
    for(int it=0;it<2;it++){
      int loff = it*4096 + tid*16;
      int row = loff >> 8;
      int L = (loff >> 4) & 15;
      int P = L ^ (row & 15);
      short8 v = *(const short8*)((const char*)lA + (row<<8) + (P<<4));
      *(short8*)((char*)Yb + (size_t)row*512 + wc0*2 + (loff&255)) = v;
    }
  }
}

// ---------------- MFMA mix. mode: 0 = mb hi/lo (+bias); 1 = m f32 (+bias); 3 = m += (no bias)
template<int NCH>
__global__ __launch_bounds__(256) void k_mix(const u16* c0,const u16* c1,const u16* c2,const u16* c3,
                                             const u16* c4,const u16* c5,const u16* c6,
                                             int wcol0,
                                             const u16* __restrict__ WH, const u16* __restrict__ WL,
                                             const float* __restrict__ bm,
                                             float* __restrict__ m, u16* __restrict__ mbh, u16* __restrict__ mbl,
                                             int mode){
  __shared__ __align__(16) u16 lds[2][8192];
  int tid = threadIdx.x, bid = blockIdx.x;
  int b = bid >> 8, t = bid & 255;
  size_t cbase = ((size_t)(b*256 + t)) * 8192;
  const u16* chp[7] = {c0,c1,c2,c3,c4,c5,c6};
  int lane = tid & 63, wave = tid >> 6;

  short8 wh[NCH][2], wl[NCH][2];
  #pragma unroll
  for(int k=0;k<NCH;k++)
    #pragma unroll
    for(int ot=0;ot<2;ot++){
      int wi = (ot*16 + (lane&15))*224 + (wcol0 + k)*32 + (lane>>4)*8;
      wh[k][ot] = *(const short8*)(WH + wi);
      wl[k][ot] = *(const short8*)(WL + wi);
    }

  {
    const u16* g = chp[0] + cbase;
    #pragma unroll
    for(int i=0;i<4;i++){
      int off = i*4096 + tid*16;
      int c = off>>9, byte = off&511;
      short8 v = *(const short8*)(g + (off>>1));
      *(short8*)((char*)&lds[0][0] + c*512 + (byte ^ ((c&24)<<2))) = v;
    }
  }
  __syncthreads();

  f32x4 acc[2][4];
  #pragma unroll
  for(int a=0;a<2;a++)
    #pragma unroll
    for(int q=0;q<4;q++) acc[a][q] = {0.f,0.f,0.f,0.f};

  int buf = 0;
  #pragma unroll
  for(int k=0;k<NCH;k++){
    if(k+1 < NCH){
      const u16* g = chp[k+1] + cbase;
      #pragma unroll
      for(int i=0;i<4;i++){
        int off = i*4096 + tid*16;
        int c = off>>9, byte = off&511;
        short8 v = *(const short8*)(g + (off>>1));
        *(short8*)((char*)&lds[buf^1][0] + c*512 + (byte ^ ((c&24)<<2))) = v;
      }
    }
    #pragma unroll
    for(int nf=0; nf<4; nf++){
      int n = (wave<<6) + (nf<<4) + (lane & 15);
      short8 v;
      #pragma unroll
      for(int j=0;j<8;j++){
        int c = ((lane>>4)<<3) + j;
        v[j] = *(const short*)((const char*)&lds[buf][0] + c*512 + ((n*2) ^ ((c&24)<<2)));
      }
      #pragma unroll
      for(int ot=0;ot<2;ot++){
        acc[ot][nf] = __builtin_amdgcn_mfma_f32_16x16x32_bf16(wh[k][ot], v, acc[ot][nf], 0,0,0);
        acc[ot][nf] = __builtin_amdgcn_mfma_f32_16x16x32_bf16(wl[k][ot], v, acc[ot][nf], 0,0,0);
      }
    }
    __syncthreads();
    buf ^= 1;
  }

  #pragma unroll
  for(int ot=0;ot<2;ot++)
    #pragma unroll
    for(int nf=0;nf<4;nf++)
      #pragma unroll
      for(int rr=0;rr<4;rr++){
        int o = ot*16 + (lane>>4)*4 + rr;
        int n = (wave<<6) + (nf<<4) + (lane&15);
        size_t a = cbase + (size_t)o*256 + n;
        float val = acc[ot][nf][rr];
        if(!(mode & 2)) val += bm[o];
        if(mode & 1){
          if(mode & 2) m[a] += val; else m[a] = val;
        } else {
          u16 hh = f2bf(val);
          mbh[a] = hh;
          mbl[a] = f2bf(val - bf2f(hh));
        }
      }
}

// ---------------- m f32 -> mb hi/lo bf16 (tier C)
__global__ __launch_bounds__(256) void k_h2b(const float* __restrict__ m, u16* __restrict__ mbh, u16* __restrict__ mbl){
  size_t i = ((size_t)blockIdx.x*256 + threadIdx.x)*4;
  f32x4 v = *(const f32x4*)(m + i);
  short4v h, l;
  #pragma unroll
  for(int j=0;j<4;j++){
    u16 hh = f2bf(v[j]);
    h[j] = (short)hh;
    l[j] = (short)f2bf(v[j] - bf2f(hh));
  }
  *(short4v*)(mbh + i) = h;
  *(short4v*)(mbl + i) = l;
}

// ---------------- m [b][t][o][n] f32 -> dst [b][o][n][t] f32
__global__ __launch_bounds__(256) void k_tip(const float* __restrict__ m, float* __restrict__ dst){
  int tile = blockIdx.x & 15; int slice = blockIdx.x >> 4;
  int b = slice >> 5, o = slice & 31;
  int tn0 = (tile & 3) * 64, tt0 = (tile >> 2) * 64;
  __shared__ float l[64][65];
  int cc = threadIdx.x & 63, r0 = threadIdx.x >> 6;
  #pragma unroll
  for(int k=0;k<16;k++){ int r = r0 + 4*k;
    l[r][cc] = m[(((size_t)b*256 + (tt0+r))*32 + o)*256 + tn0 + cc];
  }
  __syncthreads();
  #pragma unroll
  for(int k=0;k<16;k++){ int r = r0 + 4*k;
    dst[(((size_t)b*32 + o)*256 + (tn0+r))*256 + tt0 + cc] = l[cc][r];
  }
}

extern "C" void kernel_launch(void* const* d_in, const int* in_sizes, int n_in,
                              void* d_out, int out_size, void* d_ws, size_t ws_size,
                              hipStream_t stream){
  (void)in_sizes; (void)n_in; (void)out_size;
  const float* x    = (const float*)d_in[0];
  const float* nv1  = (const float*)d_in[1];
  const float* nv2  = (const float*)d_in[2];
  const float* sup0 = (const float*)d_in[3];
  const float* sup1 = (const float*)d_in[4];
  const float* wf1 = (const float*)d_in[5];  const float* bf1v = (const float*)d_in[6];
  const float* wg1 = (const float*)d_in[7];  const float* bg1v = (const float*)d_in[8];
  const float* wf2 = (const float*)d_in[9];  const float* bf2v = (const float*)d_in[10];
  const float* wg2 = (const float*)d_in[11]; const float* bg2v = (const float*)d_in[12];
  const float* wm1 = (const float*)d_in[13]; const float* bm1 = (const float*)d_in[14];
  const float* wm2 = (const float*)d_in[15]; const float* bm2 = (const float*)d_in[16];
  float* out = (float*)d_out;
  char* ws = (char*)d_ws;
  const size_t MB = (size_t)1 << 20;

  u16*  badj  = (u16*)ws;
  u16*  badj2 = (u16*)(ws + 393216);
  float* adp  = (float*)(ws + 786432);
  u16*  whi   = (u16*)(ws + 1048576);
  u16*  wlo   = (u16*)(ws + 1077248);
  u16*  wcp   = (u16*)(ws + 1105920);

  int tier = (ws_size >= 178*MB) ? 0 : ((ws_size >= 146*MB) ? 1 : 2);
  u16* h = (u16*)(ws + 2*MB);
  u16 *xT, *mbh, *mbl, *Y[6] = {0,0,0,0,0,0};
  float *m, *tmp = nullptr;
  if(tier <= 1){
    for(int k=0;k<6;k++) Y[k] = (u16*)(ws + (18 + 16*(size_t)k)*MB);
    mbh = (u16*)(ws + 114*MB); xT = mbh;
    mbl = (u16*)(ws + 130*MB);
    if(tier==0){ m = (float*)(ws + 146*MB); }
    else { m = out; tmp = (float*)(ws + 18*MB); }
  } else {
    Y[0] = (u16*)(ws + 18*MB);
    Y[1] = (u16*)(ws + 34*MB);
    xT = Y[0]; mbh = Y[0]; mbl = Y[1];
    m = out; tmp = (float*)(ws + 18*MB);
  }

  k_adp<<<256,256,0,stream>>>(nv1, nv2, adp);
  k_badj<<<768,256,0,stream>>>(sup0, sup1, adp, badj);
  k_wprep<<<88,256,0,stream>>>(wm1, wm2, wf1, wg1, wf2, wg2, whi, wlo, wcp);
  k_asq<<<12,256,0,stream>>>(badj, sup0, sup1, adp, badj2);
  k_tin<<<2048,256,0,stream>>>(x, xT);

  for(int blk=0; blk<2; blk++){
    if(blk==0) k_cv<0><<<1024,256,0,stream>>>(xT, (const u16*)0, wcp, 0, 1, bf1v, bg1v, h);
    else       k_cv<1><<<1024,256,0,stream>>>(mbh, mbl,          wcp, 1, 2, bf2v, bg2v, h);
    const u16* WH = whi + blk*7168;
    const u16* WL = wlo + blk*7168;
    const float* bm = blk ? bm2 : bm1;
    if(tier <= 1){
      k_hop<<<6144,256,0,stream>>>(h, Y[0],Y[1],Y[2],Y[3],Y[4],Y[5], badj, badj2, 0);
      if(blk==0) k_mix<7><<<1024,256,0,stream>>>(h,Y[0],Y[1],Y[2],Y[3],Y[4],Y[5], 0, WH,WL,bm, (float*)0, mbh, mbl, 0);
      else       k_mix<7><<<1024,256,0,stream>>>(h,Y[0],Y[1],Y[2],Y[3],Y[4],Y[5], 0, WH,WL,bm, m, (u16*)0, (u16*)0, 1);
    } else {
      k_mix<1><<<1024,256,0,stream>>>(h,0,0,0,0,0,0, 0, WH,WL,bm, m, (u16*)0, (u16*)0, 1);
      for(int s=0;s<3;s++){
        k_hop<<<2048,256,0,stream>>>(h, Y[0],Y[1],0,0,0,0, badj, badj2, s);
        k_mix<2><<<1024,256,0,stream>>>(Y[0],Y[1],0,0,0,0,0, 1+2*s, WH,WL,bm, m, (u16*)0, (u16*)0, 3);
      }
      if(blk==0) k_h2b<<<8192,256,0,stream>>>(m, mbh, mbl);
    }
  }
  if(tier==0){
    k_tip<<<2048,256,0,stream>>>(m, out);
  } else {
    k_tip<<<2048,256,0,stream>>>(m, tmp);
    hipMemcpyAsync(out, tmp, (size_t)32*MB, hipMemcpyDeviceToDevice, stream);
  }
}

// Round 6
// 286.539 us; speedup vs baseline: 1.8594x; 1.8594x over previous
//
#include <hip/hip_runtime.h>
#include <hip/hip_bf16.h>
#include <stdint.h>

typedef unsigned short u16;
typedef __attribute__((ext_vector_type(8))) short short8;
typedef __attribute__((ext_vector_type(4))) short short4v;
typedef __attribute__((ext_vector_type(4))) float f32x4;

__device__ __forceinline__ float bf2f(u16 b){ union {unsigned u; float f;} v; v.u = ((unsigned)b)<<16; return v.f; }
__device__ __forceinline__ u16 f2bf(float f){ union {unsigned u; float f;} v; v.f = f; unsigned r = v.u + 0x7FFF + ((v.u>>16)&1); return (u16)(r>>16); }

// ---------------- adaptive adjacency
__global__ __launch_bounds__(256) void k_adp(const float* __restrict__ nv1, const float* __restrict__ nv2,
                                             float* __restrict__ adp){
  int row = blockIdx.x; int j = threadIdx.x;
  float s = 0.f;
  #pragma unroll
  for(int k=0;k<10;k++) s = fmaf(nv1[row*10+k], nv2[k*256+j], s);
  s = s > 0.f ? s : 0.f;
  float val = (s == 0.f) ? -1e10f : s;
  __shared__ float red[256];
  red[j] = val; __syncthreads();
  for(int off=128; off>0; off>>=1){ if(j<off) red[j] = fmaxf(red[j], red[j+off]); __syncthreads(); }
  float mx = red[0]; __syncthreads();
  float e = __expf(val - mx);
  red[j] = e; __syncthreads();
  for(int off=128; off>0; off>>=1){ if(j<off) red[j] += red[j+off]; __syncthreads(); }
  adp[row*256+j] = e / red[0];
}

// ---------------- badj[s][w][v] = src_s[v][w]
__global__ __launch_bounds__(256) void k_badj(const float* __restrict__ s0, const float* __restrict__ s1,
                                              const float* __restrict__ adp, u16* __restrict__ badj){
  int s = blockIdx.x >> 8; int w = blockIdx.x & 255; int v = threadIdx.x;
  const float* src = s==0 ? s0 : (s==1 ? s1 : adp);
  badj[(s<<16) + (w<<8) + v] = f2bf(src[v*256 + w]);
}

// ---------------- weight prep
__global__ __launch_bounds__(256) void k_wprep(const float* __restrict__ wm1, const float* __restrict__ wm2,
                                               const float* __restrict__ wf1, const float* __restrict__ wg1,
                                               const float* __restrict__ wf2, const float* __restrict__ wg2,
                                               u16* __restrict__ whi, u16* __restrict__ wlo,
                                               u16* __restrict__ wcp){
  int idx = blockIdx.x*256 + threadIdx.x;
  if(idx < 14336){
    float w = (idx < 7168) ? wm1[idx] : wm2[idx-7168];
    u16 hh = f2bf(w);
    whi[idx] = hh;
    wlo[idx] = f2bf(w - bf2f(hh));
  } else {
    int e = idx - 14336;
    int blk = e >> 12; int rem = e & 4095;
    int row = rem >> 6; int kk = rem & 63;
    int tap = kk >> 5; int i = kk & 31; int o = row & 31;
    const float* wsrc = blk ? (row<32 ? wf2 : wg2) : (row<32 ? wf1 : wg1);
    float w = wsrc[(o*32+i)*2 + tap];
    u16 hh = f2bf(w);
    wcp[blk*8192 + 0    + rem] = hh;
    wcp[blk*8192 + 4096 + rem] = f2bf(w - bf2f(hh));
  }
}

// ---------------- x [b][c][n][t] f32 -> xT [b][t][c][n] bf16
__global__ __launch_bounds__(256) void k_tin(const float* __restrict__ x, u16* __restrict__ xT){
  int tile = blockIdx.x & 15; int slice = blockIdx.x >> 4;
  int b = slice >> 5, c = slice & 31;
  int tn0 = (tile & 3) * 64;
  int tt0 = (tile >> 2) * 64;
  const float* src = x + (size_t)slice*65536;
  __shared__ float l[64][65];
  int cc = threadIdx.x & 63, r0 = threadIdx.x >> 6;
  #pragma unroll
  for(int k=0;k<16;k++){ int r = r0 + 4*k;
    l[r][cc] = src[(size_t)(tn0 + r)*256 + tt0 + cc];
  }
  __syncthreads();
  #pragma unroll
  for(int k=0;k<16;k++){ int r = r0 + 4*k;
    xT[(((size_t)b*256 + (tt0+r))*32 + c)*256 + tn0 + cc] = f2bf(l[cc][r]);
  }
}

// ---------------- badj2[s] = badj[s] . badj[s]  (= (A^2)^T stored [w][v])
__global__ __launch_bounds__(256) void k_asq(const u16* __restrict__ badj,
                                             const float* __restrict__ s0, const float* __restrict__ s1,
                                             const float* __restrict__ adp, u16* __restrict__ badj2){
  __shared__ __align__(16) u16 lds[16384];
  int tid = threadIdx.x, bid = blockIdx.x;
  int s = bid >> 2, rt = bid & 3;
  int w0 = rt << 6;
  const u16* T = badj + (s<<16);
  const float* S = s==0 ? s0 : (s==1 ? s1 : adp);
  #pragma unroll
  for(int i=0;i<8;i++){
    int off = i*4096 + tid*16;
    int row = off >> 9;
    int P = (off >> 4) & 31;
    int L = (P & 16) | ((P & 15) ^ (row & 15));
    short8 v = *(const short8*)((const char*)T + (size_t)(w0 + row)*512 + L*16);
    *(short8*)((char*)lds + off) = v;
  }
  __syncthreads();
  int lane = tid & 63, wave = tid >> 6;
  int wr = (wave >> 1) << 5, wc = (wave & 1) << 7;
  f32x4 acc[2][8];
  #pragma unroll
  for(int a=0;a<2;a++)
    #pragma unroll
    for(int q=0;q<8;q++) acc[a][q] = {0.f,0.f,0.f,0.f};
  for(int ks=0; ks<8; ks++){
    short8 afr[2], bfr[8];
    #pragma unroll
    for(int mf=0; mf<2; mf++){
      int row = wr + mf*16 + (lane & 15);
      int L = ks*4 + (lane >> 4);
      int P = (L & 16) | ((L & 15) ^ (row & 15));
      afr[mf] = *(const short8*)&lds[row*256 + P*8];
    }
    #pragma unroll
    for(int nf=0; nf<8; nf++){
      int col = wc + nf*16 + (lane & 15);
      const float* src = S + (size_t)col*256 + ks*32 + (lane>>4)*8;
      #pragma unroll
      for(int jj=0;jj<8;jj++) bfr[nf][jj] = (short)f2bf(src[jj]);
    }
    #pragma unroll
    for(int mf=0;mf<2;mf++)
      #pragma unroll
      for(int nf=0;nf<8;nf++)
        acc[mf][nf] = __builtin_amdgcn_mfma_f32_16x16x32_bf16(afr[mf], bfr[nf], acc[mf][nf], 0,0,0);
  }
  u16* D = badj2 + (s<<16) + (size_t)w0*256;
  #pragma unroll
  for(int mf=0;mf<2;mf++)
    #pragma unroll
    for(int nf=0;nf<8;nf++)
      #pragma unroll
      for(int rr=0;rr<4;rr++){
        int row = wr + mf*16 + (lane>>4)*4 + rr;
        int col = wc + nf*16 + (lane&15);
        D[row*256 + col] = f2bf(acc[mf][nf][rr]);
      }
}

// ---------------- pack adjacency into MFMA B-fragment order:
// bpack[((s*2+mat)*8+ks)*16+cg][lane][j] = adjT[cg*16+(lane&15)][ks*32+(lane>>4)*8+j]
// total threads = 3*2*8*16*64 = 49152 -> grid 192
__global__ __launch_bounds__(256) void k_pack(const u16* __restrict__ badj, const u16* __restrict__ badj2,
                                              u16* __restrict__ bpack){
  int t = blockIdx.x*256 + threadIdx.x;      // < 49152
  int lane = t & 63; int cg = (t>>6)&15; int ks = (t>>10)&7; int mat = (t>>13)&1; int s = t>>14;
  const u16* src = (mat ? badj2 : badj) + (s<<16) + (cg*16 + (lane&15))*256 + ks*32 + (lane>>4)*8;
  short8 v = *(const short8*)src;
  *(short8*)(bpack + (size_t)t*8) = v;
}

// ---------------- MFMA gated conv (+bias, sigmoid gate)
template<int HILO>
__global__ __launch_bounds__(256) void k_cv(const u16* __restrict__ X0, const u16* __restrict__ X1,
                                            const u16* __restrict__ wcp, int blk, int dil,
                                            const float* __restrict__ bfv, const float* __restrict__ bgv,
                                            u16* __restrict__ outh){
  __shared__ __align__(16) u16 pl[(1+HILO)*2*8192];
  const int NPART = 1+HILO;
  int tid = threadIdx.x, bid = blockIdx.x;
  int b = bid >> 8, t = bid & 255;
  size_t base_cur = ((size_t)(b*256 + t))*8192;
  const u16* Xs[2] = {X0, X1};
  #pragma unroll
  for(int part=0; part<NPART; part++){
    #pragma unroll
    for(int tap=0; tap<2; tap++){
      bool valid = (tap==1) || (t >= dil);
      const u16* src = Xs[part] + base_cur - (tap==0 ? (size_t)dil*8192 : 0);
      char* pb = (char*)pl + (tap*NPART + part)*16384;
      #pragma unroll
      for(int it=0; it<4; it++){
        int off = it*4096 + tid*16;
        int c = off >> 9;
        int byte = off & 511;
        short8 v = {0,0,0,0,0,0,0,0};
        if(valid) v = *(const short8*)(src + (off>>1));
        *(short8*)(pb + c*512 + (byte ^ ((c&24)<<2))) = v;
      }
    }
  }
  int lane = tid & 63, wave = tid >> 6;
  const u16* wb = wcp + blk*8192;
  short8 wfr[4][2][2];
  #pragma unroll
  for(int ot=0;ot<4;ot++)
    #pragma unroll
    for(int ks=0;ks<2;ks++)
      #pragma unroll
      for(int p=0;p<2;p++)
        wfr[ot][ks][p] = *(const short8*)(wb + p*4096 + (ot*16 + (lane&15))*64 + ks*32 + (lane>>4)*8);
  __syncthreads();

  f32x4 acc[4][4];
  #pragma unroll
  for(int a=0;a<4;a++)
    #pragma unroll
    for(int q=0;q<4;q++) acc[a][q] = {0.f,0.f,0.f,0.f};
  int nbase = wave << 6;
  #pragma unroll
  for(int nf=0; nf<4; nf++){
    int n = nbase + nf*16 + (lane & 15);
    #pragma unroll
    for(int ks=0; ks<2; ks++){
      short8 xv[NPART];
      #pragma unroll
      for(int p=0;p<NPART;p++){
        char* pb = (char*)pl + (ks*NPART + p)*16384;
        short8 v;
        #pragma unroll
        for(int jj=0;jj<8;jj++){
          int c = ((lane>>4)<<3) + jj;
          v[jj] = *(const short*)(pb + c*512 + ((n*2) ^ ((c&24)<<2)));
        }
        xv[p] = v;
      }
      #pragma unroll
      for(int ot=0; ot<4; ot++){
        acc[ot][nf] = __builtin_amdgcn_mfma_f32_16x16x32_bf16(wfr[ot][ks][0], xv[0], acc[ot][nf], 0,0,0);
        acc[ot][nf] = __builtin_amdgcn_mfma_f32_16x16x32_bf16(wfr[ot][ks][1], xv[0], acc[ot][nf], 0,0,0);
        if(HILO)
          acc[ot][nf] = __builtin_amdgcn_mfma_f32_16x16x32_bf16(wfr[ot][ks][0], xv[HILO], acc[ot][nf], 0,0,0);
      }
    }
  }
  u16* ob = outh + base_cur;
  #pragma unroll
  for(int ot=0; ot<2; ot++)
    #pragma unroll
    for(int nf=0; nf<4; nf++)
      #pragma unroll
      for(int rr=0; rr<4; rr++){
        int o = ot*16 + (lane>>4)*4 + rr;
        int n = nbase + nf*16 + (lane&15);
        float fv = acc[ot][nf][rr] + bfv[o];
        float gv = acc[ot+2][nf][rr] + bgv[o];
        ob[(size_t)o*256 + n] = f2bf(fv / (1.f + __expf(-gv)));
      }
}

// ---------------- hop GEMMs v3: 32-row x 128-col tile, 2 GEMMs (A_s, A_s^2) per block,
// packed-B contiguous 1KB wave loads, straight-line register code, 1-deep B prefetch.
#define LB(KS,FC) (*(const short8*)(bp + ((((KS)*16) + cg0 + (FC))<<9) + (lane<<3)))
#define MF(A,B,C) __builtin_amdgcn_mfma_f32_16x16x32_bf16((A),(B),(C),0,0,0)
template<int NSUP>
__global__ __launch_bounds__(256, 4) void k_hop(const u16* __restrict__ X,
                                                u16* __restrict__ ybase,
                                                const u16* __restrict__ bpack,
                                                int s_base){
  __shared__ __align__(16) u16 lA[8192];   // 16 KB A-tile [32 rows][32 x 16B slots], row-XOR swizzle
  __shared__ __align__(16) u16 lE[4096];   // 8 KB epilogue tile [32 rows][16 x 16B slots]
  int tid = threadIdx.x, bid = blockIdx.x;
  int ch = bid & 1;
  int t1 = bid >> 1;
  int sp = (NSUP==1) ? 0 : (t1 % NSUP);
  int u  = (NSUP==1) ? t1 : (t1 / NSUP);
  int rt = u & 255, b = u >> 8;
  int m0 = rt << 5;
  int s = s_base + sp;
  const char* Xb = (const char*)X + ((size_t)b << 22) + (size_t)m0*512;

  // stage A-tile (32 rows x 256 k) with row-XOR slot swizzle via pre-swizzled source
  #pragma unroll
  for(int i=0;i<4;i++){
    int off = i*4096 + tid*16;
    int row = off >> 9;
    int P = (off >> 4) & 31;
    int L = (P & 16) | ((P & 15) ^ (row & 15));
    short8 v = *(const short8*)(Xb + (size_t)row*512 + L*16);
    *(short8*)((char*)lA + off) = v;
  }
  __syncthreads();

  int lane = tid & 63, wave = tid >> 6;
  int wr = (wave >> 1) << 4;                 // wave rows: 0 / 16
  int cg0 = ch*8 + (wave & 1)*4;             // wave col-group base (16-col units)

  // hoist A fragments to registers (shared by both GEMMs)
  short8 af[8];
  #pragma unroll
  for(int ks=0;ks<8;ks++){
    int row = wr + (lane & 15);
    int L = ks*4 + (lane >> 4);
    int P = (L & 16) | ((L & 15) ^ (row & 15));
    af[ks] = *(const short8*)&lA[row*256 + P*8];
  }

  #pragma unroll
  for(int mat=0; mat<2; mat++){
    const u16* bp = bpack + (((size_t)s*2 + mat) << 16);
    f32x4 a0 = {0.f,0.f,0.f,0.f}, a1 = a0, a2 = a0, a3 = a0;
    short8 b0 = LB(0,0), b1 = LB(0,1), b2 = LB(0,2), b3 = LB(0,3);
    #pragma unroll
    for(int ks=0; ks<8; ks++){
      short8 n0, n1, n2, n3;
      if(ks < 7){ n0 = LB(ks+1,0); n1 = LB(ks+1,1); n2 = LB(ks+1,2); n3 = LB(ks+1,3); }
      a0 = MF(af[ks], b0, a0);
      a1 = MF(af[ks], b1, a1);
      a2 = MF(af[ks], b2, a2);
      a3 = MF(af[ks], b3, a3);
      if(ks < 7){ b0 = n0; b1 = n1; b2 = n2; b3 = n3; }
    }

    // epilogue: acc -> lE (slot-XOR swizzle) -> coalesced stores
    if(mat) __syncthreads();   // prior store's lE reads complete
    #pragma unroll
    for(int fc=0; fc<4; fc++){
      f32x4 av = fc==0 ? a0 : (fc==1 ? a1 : (fc==2 ? a2 : a3));
      #pragma unroll
      for(int rr=0; rr<4; rr++){
        int row = wr + (lane>>4)*4 + rr;
        int col = (wave&1)*64 + fc*16 + (lane&15);
        int byte = col*2;
        int L = byte >> 4;
        int P = L ^ (row & 15);
        *(u16*)((char*)lE + (row<<8) + (P<<4) + (byte&15)) = f2bf(av[rr]);
      }
    }
    __syncthreads();
    char* Yb = (char*)(ybase + (size_t)(sp*2 + mat)*8388608) + ((size_t)b<<22) + (size_t)m0*512 + ch*256;
    #pragma unroll
    for(int it=0; it<2; it++){
      int loff = it*4096 + tid*16;
      int row = loff >> 8;
      int L = (loff >> 4) & 15;
      int P = L ^ (row & 15);
      short8 v = *(const short8*)((char*)lE + (row<<8) + (P<<4));
      *(short8*)(Yb + (size_t)row*512 + (loff & 255)) = v;
    }
  }
}
#undef LB
#undef MF

// ---------------- MFMA mix. mode: 0 = mb hi/lo (+bias); 1 = m f32 (+bias); 3 = m += (no bias)
template<int NCH>
__global__ __launch_bounds__(256) void k_mix(const u16* c0,const u16* c1,const u16* c2,const u16* c3,
                                             const u16* c4,const u16* c5,const u16* c6,
                                             int wcol0,
                                             const u16* __restrict__ WH, const u16* __restrict__ WL,
                                             const float* __restrict__ bm,
                                             float* __restrict__ m, u16* __restrict__ mbh, u16* __restrict__ mbl,
                                             int mode){
  __shared__ __align__(16) u16 lds[2][8192];
  int tid = threadIdx.x, bid = blockIdx.x;
  int b = bid >> 8, t = bid & 255;
  size_t cbase = ((size_t)(b*256 + t)) * 8192;
  const u16* chp[7] = {c0,c1,c2,c3,c4,c5,c6};
  int lane = tid & 63, wave = tid >> 6;

  short8 wh[NCH][2], wl[NCH][2];
  #pragma unroll
  for(int k=0;k<NCH;k++)
    #pragma unroll
    for(int ot=0;ot<2;ot++){
      int wi = (ot*16 + (lane&15))*224 + (wcol0 + k)*32 + (lane>>4)*8;
      wh[k][ot] = *(const short8*)(WH + wi);
      wl[k][ot] = *(const short8*)(WL + wi);
    }

  {
    const u16* g = chp[0] + cbase;
    #pragma unroll
    for(int i=0;i<4;i++){
      int off = i*4096 + tid*16;
      int c = off>>9, byte = off&511;
      short8 v = *(const short8*)(g + (off>>1));
      *(short8*)((char*)&lds[0][0] + c*512 + (byte ^ ((c&24)<<2))) = v;
    }
  }
  __syncthreads();

  f32x4 acc[2][4];
  #pragma unroll
  for(int a=0;a<2;a++)
    #pragma unroll
    for(int q=0;q<4;q++) acc[a][q] = {0.f,0.f,0.f,0.f};

  int buf = 0;
  #pragma unroll
  for(int k=0;k<NCH;k++){
    if(k+1 < NCH){
      const u16* g = chp[k+1] + cbase;
      #pragma unroll
      for(int i=0;i<4;i++){
        int off = i*4096 + tid*16;
        int c = off>>9, byte = off&511;
        short8 v = *(const short8*)(g + (off>>1));
        *(short8*)((char*)&lds[buf^1][0] + c*512 + (byte ^ ((c&24)<<2))) = v;
      }
    }
    #pragma unroll
    for(int nf=0; nf<4; nf++){
      int n = (wave<<6) + (nf<<4) + (lane & 15);
      short8 v;
      #pragma unroll
      for(int j=0;j<8;j++){
        int c = ((lane>>4)<<3) + j;
        v[j] = *(const short*)((const char*)&lds[buf][0] + c*512 + ((n*2) ^ ((c&24)<<2)));
      }
      #pragma unroll
      for(int ot=0;ot<2;ot++){
        acc[ot][nf] = __builtin_amdgcn_mfma_f32_16x16x32_bf16(wh[k][ot], v, acc[ot][nf], 0,0,0);
        acc[ot][nf] = __builtin_amdgcn_mfma_f32_16x16x32_bf16(wl[k][ot], v, acc[ot][nf], 0,0,0);
      }
    }
    __syncthreads();
    buf ^= 1;
  }

  #pragma unroll
  for(int ot=0;ot<2;ot++)
    #pragma unroll
    for(int nf=0;nf<4;nf++)
      #pragma unroll
      for(int rr=0;rr<4;rr++){
        int o = ot*16 + (lane>>4)*4 + rr;
        int n = (wave<<6) + (nf<<4) + (lane&15);
        size_t a = cbase + (size_t)o*256 + n;
        float val = acc[ot][nf][rr];
        if(!(mode & 2)) val += bm[o];
        if(mode & 1){
          if(mode & 2) m[a] += val; else m[a] = val;
        } else {
          u16 hh = f2bf(val);
          mbh[a] = hh;
          mbl[a] = f2bf(val - bf2f(hh));
        }
      }
}

// ---------------- m f32 -> mb hi/lo bf16 (tier C)
__global__ __launch_bounds__(256) void k_h2b(const float* __restrict__ m, u16* __restrict__ mbh, u16* __restrict__ mbl){
  size_t i = ((size_t)blockIdx.x*256 + threadIdx.x)*4;
  f32x4 v = *(const f32x4*)(m + i);
  short4v h, l;
  #pragma unroll
  for(int j=0;j<4;j++){
    u16 hh = f2bf(v[j]);
    h[j] = (short)hh;
    l[j] = (short)f2bf(v[j] - bf2f(hh));
  }
  *(short4v*)(mbh + i) = h;
  *(short4v*)(mbl + i) = l;
}

// ---------------- m [b][t][o][n] f32 -> dst [b][o][n][t] f32
__global__ __launch_bounds__(256) void k_tip(const float* __restrict__ m, float* __restrict__ dst){
  int tile = blockIdx.x & 15; int slice = blockIdx.x >> 4;
  int b = slice >> 5, o = slice & 31;
  int tn0 = (tile & 3) * 64, tt0 = (tile >> 2) * 64;
  __shared__ float l[64][65];
  int cc = threadIdx.x & 63, r0 = threadIdx.x >> 6;
  #pragma unroll
  for(int k=0;k<16;k++){ int r = r0 + 4*k;
    l[r][cc] = m[(((size_t)b*256 + (tt0+r))*32 + o)*256 + tn0 + cc];
  }
  __syncthreads();
  #pragma unroll
  for(int k=0;k<16;k++){ int r = r0 + 4*k;
    dst[(((size_t)b*32 + o)*256 + (tn0+r))*256 + tt0 + cc] = l[cc][r];
  }
}

extern "C" void kernel_launch(void* const* d_in, const int* in_sizes, int n_in,
                              void* d_out, int out_size, void* d_ws, size_t ws_size,
                              hipStream_t stream){
  (void)in_sizes; (void)n_in; (void)out_size;
  const float* x    = (const float*)d_in[0];
  const float* nv1  = (const float*)d_in[1];
  const float* nv2  = (const float*)d_in[2];
  const float* sup0 = (const float*)d_in[3];
  const float* sup1 = (const float*)d_in[4];
  const float* wf1 = (const float*)d_in[5];  const float* bf1v = (const float*)d_in[6];
  const float* wg1 = (const float*)d_in[7];  const float* bg1v = (const float*)d_in[8];
  const float* wf2 = (const float*)d_in[9];  const float* bf2v = (const float*)d_in[10];
  const float* wg2 = (const float*)d_in[11]; const float* bg2v = (const float*)d_in[12];
  const float* wm1 = (const float*)d_in[13]; const float* bm1 = (const float*)d_in[14];
  const float* wm2 = (const float*)d_in[15]; const float* bm2 = (const float*)d_in[16];
  float* out = (float*)d_out;
  char* ws = (char*)d_ws;
  const size_t MB = (size_t)1 << 20;

  u16*  badj  = (u16*)ws;
  u16*  badj2 = (u16*)(ws + 393216);
  float* adp  = (float*)(ws + 786432);
  u16*  whi   = (u16*)(ws + 1048576);
  u16*  wlo   = (u16*)(ws + 1077248);
  u16*  wcp   = (u16*)(ws + 1105920);
  u16*  bpack = (u16*)(ws + 1179648);   // 768 KB, ends < 2 MB

  int tier = (ws_size >= 178*MB) ? 0 : ((ws_size >= 146*MB) ? 1 : 2);
  u16* h = (u16*)(ws + 2*MB);
  u16 *xT, *mbh, *mbl, *Y[6] = {0,0,0,0,0,0};
  float *m, *tmp = nullptr;
  if(tier <= 1){
    for(int k=0;k<6;k++) Y[k] = (u16*)(ws + (18 + 16*(size_t)k)*MB);
    mbh = (u16*)(ws + 114*MB); xT = mbh;
    mbl = (u16*)(ws + 130*MB);
    if(tier==0){ m = (float*)(ws + 146*MB); }
    else { m = out; tmp = (float*)(ws + 18*MB); }
  } else {
    Y[0] = (u16*)(ws + 18*MB);
    Y[1] = (u16*)(ws + 34*MB);
    xT = Y[0]; mbh = Y[0]; mbl = Y[1];
    m = out; tmp = (float*)(ws + 18*MB);
  }

  k_adp<<<256,256,0,stream>>>(nv1, nv2, adp);
  k_badj<<<768,256,0,stream>>>(sup0, sup1, adp, badj);
  k_wprep<<<88,256,0,stream>>>(wm1, wm2, wf1, wg1, wf2, wg2, whi, wlo, wcp);
  k_asq<<<12,256,0,stream>>>(badj, sup0, sup1, adp, badj2);
  k_pack<<<192,256,0,stream>>>(badj, badj2, bpack);
  k_tin<<<2048,256,0,stream>>>(x, xT);

  for(int blk=0; blk<2; blk++){
    if(blk==0) k_cv<0><<<1024,256,0,stream>>>(xT, (const u16*)0, wcp, 0, 1, bf1v, bg1v, h);
    else       k_cv<1><<<1024,256,0,stream>>>(mbh, mbl,          wcp, 1, 2, bf2v, bg2v, h);
    const u16* WH = whi + blk*7168;
    const u16* WL = wlo + blk*7168;
    const float* bm = blk ? bm2 : bm1;
    if(tier <= 1){
      k_hop<3><<<6144,256,0,stream>>>(h, Y[0], bpack, 0);
      if(blk==0) k_mix<7><<<1024,256,0,stream>>>(h,Y[0],Y[1],Y[2],Y[3],Y[4],Y[5], 0, WH,WL,bm, (float*)0, mbh, mbl, 0);
      else       k_mix<7><<<1024,256,0,stream>>>(h,Y[0],Y[1],Y[2],Y[3],Y[4],Y[5], 0, WH,WL,bm, m, (u16*)0, (u16*)0, 1);
    } else {
      k_mix<1><<<1024,256,0,stream>>>(h,0,0,0,0,0,0, 0, WH,WL,bm, m, (u16*)0, (u16*)0, 1);
      for(int s=0;s<3;s++){
        k_hop<1><<<2048,256,0,stream>>>(h, Y[0], bpack, s);
        k_mix<2><<<1024,256,0,stream>>>(Y[0],Y[1],0,0,0,0,0, 1+2*s, WH,WL,bm, m, (u16*)0, (u16*)0, 3);
      }
      if(blk==0) k_h2b<<<8192,256,0,stream>>>(m, mbh, mbl);
    }
  }
  if(tier==0){
    k_tip<<<2048,256,0,stream>>>(m, out);
  } else {
    k_tip<<<2048,256,0,stream>>>(m, tmp);
    hipMemcpyAsync(out, tmp, (size_t)32*MB, hipMemcpyDeviceToDevice, stream);
  }
}

// Round 7
// 248.512 us; speedup vs baseline: 2.1440x; 1.1530x over previous
//
#include <hip/hip_runtime.h>
#include <hip/hip_bf16.h>
#include <stdint.h>

typedef unsigned short u16;
typedef __attribute__((ext_vector_type(8))) short short8;
typedef __attribute__((ext_vector_type(4))) float f32x4;

__device__ __forceinline__ float bf2f(u16 b){ union {unsigned u; float f;} v; v.u = ((unsigned)b)<<16; return v.f; }
__device__ __forceinline__ u16 f2bf(float f){ union {unsigned u; float f;} v; v.f = f; unsigned r = v.u + 0x7FFF + ((v.u>>16)&1); return (u16)(r>>16); }

// ---------------- adaptive adjacency
__global__ __launch_bounds__(256) void k_adp(const float* __restrict__ nv1, const float* __restrict__ nv2,
                                             float* __restrict__ adp){
  int row = blockIdx.x; int j = threadIdx.x;
  float s = 0.f;
  #pragma unroll
  for(int k=0;k<10;k++) s = fmaf(nv1[row*10+k], nv2[k*256+j], s);
  s = s > 0.f ? s : 0.f;
  float val = (s == 0.f) ? -1e10f : s;
  __shared__ float red[256];
  red[j] = val; __syncthreads();
  for(int off=128; off>0; off>>=1){ if(j<off) red[j] = fmaxf(red[j], red[j+off]); __syncthreads(); }
  float mx = red[0]; __syncthreads();
  float e = __expf(val - mx);
  red[j] = e; __syncthreads();
  for(int off=128; off>0; off>>=1){ if(j<off) red[j] += red[j+off]; __syncthreads(); }
  adp[row*256+j] = e / red[0];
}

// ---------------- badj[s][w][v] = src_s[v][w]
__global__ __launch_bounds__(256) void k_badj(const float* __restrict__ s0, const float* __restrict__ s1,
                                              const float* __restrict__ adp, u16* __restrict__ badj){
  int s = blockIdx.x >> 8; int w = blockIdx.x & 255; int v = threadIdx.x;
  const float* src = s==0 ? s0 : (s==1 ? s1 : adp);
  badj[(s<<16) + (w<<8) + v] = f2bf(src[v*256 + w]);
}

// ---------------- weight prep
__global__ __launch_bounds__(256) void k_wprep(const float* __restrict__ wm1, const float* __restrict__ wm2,
                                               const float* __restrict__ wf1, const float* __restrict__ wg1,
                                               const float* __restrict__ wf2, const float* __restrict__ wg2,
                                               u16* __restrict__ whi, u16* __restrict__ wlo,
                                               u16* __restrict__ wcp){
  int idx = blockIdx.x*256 + threadIdx.x;
  if(idx < 14336){
    float w = (idx < 7168) ? wm1[idx] : wm2[idx-7168];
    u16 hh = f2bf(w);
    whi[idx] = hh;
    wlo[idx] = f2bf(w - bf2f(hh));
  } else {
    int e = idx - 14336;
    int blk = e >> 12; int rem = e & 4095;
    int row = rem >> 6; int kk = rem & 63;
    int tap = kk >> 5; int i = kk & 31; int o = row & 31;
    const float* wsrc = blk ? (row<32 ? wf2 : wg2) : (row<32 ? wf1 : wg1);
    float w = wsrc[(o*32+i)*2 + tap];
    u16 hh = f2bf(w);
    wcp[blk*8192 + 0    + rem] = hh;
    wcp[blk*8192 + 4096 + rem] = f2bf(w - bf2f(hh));
  }
}

// ---------------- x [b][c][n][t] f32 -> xT [b][t][c][n] bf16
__global__ __launch_bounds__(256) void k_tin(const float* __restrict__ x, u16* __restrict__ xT){
  int tile = blockIdx.x & 15; int slice = blockIdx.x >> 4;
  int b = slice >> 5, c = slice & 31;
  int tn0 = (tile & 3) * 64;
  int tt0 = (tile >> 2) * 64;
  const float* src = x + (size_t)slice*65536;
  __shared__ float l[64][65];
  int cc = threadIdx.x & 63, r0 = threadIdx.x >> 6;
  #pragma unroll
  for(int k=0;k<16;k++){ int r = r0 + 4*k;
    l[r][cc] = src[(size_t)(tn0 + r)*256 + tt0 + cc];
  }
  __syncthreads();
  #pragma unroll
  for(int k=0;k<16;k++){ int r = r0 + 4*k;
    xT[(((size_t)b*256 + (tt0+r))*32 + c)*256 + tn0 + cc] = f2bf(l[cc][r]);
  }
}

// ---------------- badj2[s] = badj[s] . badj[s]  (= (A^2)^T stored [w][v])
__global__ __launch_bounds__(256) void k_asq(const u16* __restrict__ badj,
                                             const float* __restrict__ s0, const float* __restrict__ s1,
                                             const float* __restrict__ adp, u16* __restrict__ badj2){
  __shared__ __align__(16) u16 lds[16384];
  int tid = threadIdx.x, bid = blockIdx.x;
  int s = bid >> 2, rt = bid & 3;
  int w0 = rt << 6;
  const u16* T = badj + (s<<16);
  const float* S = s==0 ? s0 : (s==1 ? s1 : adp);
  #pragma unroll
  for(int i=0;i<8;i++){
    int off = i*4096 + tid*16;
    int row = off >> 9;
    int P = (off >> 4) & 31;
    int L = (P & 16) | ((P & 15) ^ (row & 15));
    short8 v = *(const short8*)((const char*)T + (size_t)(w0 + row)*512 + L*16);
    *(short8*)((char*)lds + off) = v;
  }
  __syncthreads();
  int lane = tid & 63, wave = tid >> 6;
  int wr = (wave >> 1) << 5, wc = (wave & 1) << 7;
  f32x4 acc[2][8];
  #pragma unroll
  for(int a=0;a<2;a++)
    #pragma unroll
    for(int q=0;q<8;q++) acc[a][q] = {0.f,0.f,0.f,0.f};
  for(int ks=0; ks<8; ks++){
    short8 afr[2], bfr[8];
    #pragma unroll
    for(int mf=0; mf<2; mf++){
      int row = wr + mf*16 + (lane & 15);
      int L = ks*4 + (lane >> 4);
      int P = (L & 16) | ((L & 15) ^ (row & 15));
      afr[mf] = *(const short8*)&lds[row*256 + P*8];
    }
    #pragma unroll
    for(int nf=0; nf<8; nf++){
      int col = wc + nf*16 + (lane & 15);
      const float* src = S + (size_t)col*256 + ks*32 + (lane>>4)*8;
      #pragma unroll
      for(int jj=0;jj<8;jj++) bfr[nf][jj] = (short)f2bf(src[jj]);
    }
    #pragma unroll
    for(int mf=0;mf<2;mf++)
      #pragma unroll
      for(int nf=0;nf<8;nf++)
        acc[mf][nf] = __builtin_amdgcn_mfma_f32_16x16x32_bf16(afr[mf], bfr[nf], acc[mf][nf], 0,0,0);
  }
  u16* D = badj2 + (s<<16) + (size_t)w0*256;
  #pragma unroll
  for(int mf=0;mf<2;mf++)
    #pragma unroll
    for(int nf=0;nf<8;nf++)
      #pragma unroll
      for(int rr=0;rr<4;rr++){
        int row = wr + mf*16 + (lane>>4)*4 + rr;
        int col = wc + nf*16 + (lane&15);
        D[row*256 + col] = f2bf(acc[mf][nf][rr]);
      }
}

// ---------------- pack adjacency into MFMA B-fragment order (49152 threads -> grid 192)
__global__ __launch_bounds__(256) void k_pack(const u16* __restrict__ badj, const u16* __restrict__ badj2,
                                              u16* __restrict__ bpack){
  int t = blockIdx.x*256 + threadIdx.x;      // < 49152
  int lane = t & 63; int cg = (t>>6)&15; int ks = (t>>10)&7; int mat = (t>>13)&1; int s = t>>14;
  const u16* src = (mat ? badj2 : badj) + (s<<16) + (cg*16 + (lane&15))*256 + ks*32 + (lane>>4)*8;
  short8 v = *(const short8*)src;
  *(short8*)(bpack + (size_t)t*8) = v;
}

// ---------------- MFMA gated conv (+bias, sigmoid gate)
template<int HILO>
__global__ __launch_bounds__(256) void k_cv(const u16* __restrict__ X0, const u16* __restrict__ X1,
                                            const u16* __restrict__ wcp, int blk, int dil,
                                            const float* __restrict__ bfv, const float* __restrict__ bgv,
                                            u16* __restrict__ outh){
  __shared__ __align__(16) u16 pl[(1+HILO)*2*8192];
  const int NPART = 1+HILO;
  int tid = threadIdx.x, bid = blockIdx.x;
  int b = bid >> 8, t = bid & 255;
  size_t base_cur = ((size_t)(b*256 + t))*8192;
  const u16* Xs[2] = {X0, X1};
  #pragma unroll
  for(int part=0; part<NPART; part++){
    #pragma unroll
    for(int tap=0; tap<2; tap++){
      bool valid = (tap==1) || (t >= dil);
      const u16* src = Xs[part] + base_cur - (tap==0 ? (size_t)dil*8192 : 0);
      char* pb = (char*)pl + (tap*NPART + part)*16384;
      #pragma unroll
      for(int it=0; it<4; it++){
        int off = it*4096 + tid*16;
        int c = off >> 9;
        int byte = off & 511;
        short8 v = {0,0,0,0,0,0,0,0};
        if(valid) v = *(const short8*)(src + (off>>1));
        *(short8*)(pb + c*512 + (byte ^ ((c&24)<<2))) = v;
      }
    }
  }
  int lane = tid & 63, wave = tid >> 6;
  const u16* wb = wcp + blk*8192;
  short8 wfr[4][2][2];
  #pragma unroll
  for(int ot=0;ot<4;ot++)
    #pragma unroll
    for(int ks=0;ks<2;ks++)
      #pragma unroll
      for(int p=0;p<2;p++)
        wfr[ot][ks][p] = *(const short8*)(wb + p*4096 + (ot*16 + (lane&15))*64 + ks*32 + (lane>>4)*8);
  __syncthreads();

  f32x4 acc[4][4];
  #pragma unroll
  for(int a=0;a<4;a++)
    #pragma unroll
    for(int q=0;q<4;q++) acc[a][q] = {0.f,0.f,0.f,0.f};
  int nbase = wave << 6;
  #pragma unroll
  for(int nf=0; nf<4; nf++){
    int n = nbase + nf*16 + (lane & 15);
    #pragma unroll
    for(int ks=0; ks<2; ks++){
      short8 xv[NPART];
      #pragma unroll
      for(int p=0;p<NPART;p++){
        char* pb = (char*)pl + (ks*NPART + p)*16384;
        short8 v;
        #pragma unroll
        for(int jj=0;jj<8;jj++){
          int c = ((lane>>4)<<3) + jj;
          v[jj] = *(const short*)(pb + c*512 + ((n*2) ^ ((c&24)<<2)));
        }
        xv[p] = v;
      }
      #pragma unroll
      for(int ot=0; ot<4; ot++){
        acc[ot][nf] = __builtin_amdgcn_mfma_f32_16x16x32_bf16(wfr[ot][ks][0], xv[0], acc[ot][nf], 0,0,0);
        acc[ot][nf] = __builtin_amdgcn_mfma_f32_16x16x32_bf16(wfr[ot][ks][1], xv[0], acc[ot][nf], 0,0,0);
        if(HILO)
          acc[ot][nf] = __builtin_amdgcn_mfma_f32_16x16x32_bf16(wfr[ot][ks][0], xv[HILO], acc[ot][nf], 0,0,0);
      }
    }
  }
  u16* ob = outh + base_cur;
  #pragma unroll
  for(int ot=0; ot<2; ot++)
    #pragma unroll
    for(int nf=0; nf<4; nf++)
      #pragma unroll
      for(int rr=0; rr<4; rr++){
        int o = ot*16 + (lane>>4)*4 + rr;
        int n = nbase + nf*16 + (lane&15);
        float fv = acc[ot][nf][rr] + bfv[o];
        float gv = acc[ot+2][nf][rr] + bgv[o];
        ob[(size_t)o*256 + n] = f2bf(fv / (1.f + __expf(-gv)));
      }
}

// ---------------- swizzled-LDS gather of a mix B-fragment: c = khi*8+j rows, col n
__device__ __forceinline__ short8 gath(const u16* TB, int n, int khi){
  short8 v; int Lc = n >> 3; int bb = (n & 7) * 2;
  #pragma unroll
  for(int j=0;j<8;j++){
    int c = khi*8 + j;
    int P = (Lc & 16) | ((Lc & 15) ^ (c & 15));
    v[j] = *(const u16*)((const char*)TB + c*512 + P*16 + bb);
  }
  return v;
}

// ---------------- fused hop+mix: per (b,t) block. A = h[b][t] in LDS; 6 GEMMs vs packed
// adjacency write Y-tiles to LDS only; mix accumulates OUT with hi/lo W MFMAs.
// MODE 0: OUT -> mbh/mbl bf16 pair (+bias). MODE 1: OUT -> m f32 (+bias).
#define LB(KS,FC) (*(const short8*)(bp + ((((KS)*16) + cg0 + (FC))<<9) + (lane<<3)))
#define MF(A,B,C) __builtin_amdgcn_mfma_f32_16x16x32_bf16((A),(B),(C),0,0,0)
template<int MODE>
__global__ __launch_bounds__(256, 3) void k_fuse(const u16* __restrict__ X,
                                                 const u16* __restrict__ bpack,
                                                 const u16* __restrict__ WH, const u16* __restrict__ WL,
                                                 const float* __restrict__ bm,
                                                 float* __restrict__ m, u16* __restrict__ mbh, u16* __restrict__ mbl){
  __shared__ __align__(16) u16 lA[8192];   // h tile [32 c][256 n], row-XOR-slot swizzle
  __shared__ __align__(16) u16 lY[8192];   // current Y tile, same layout
  int tid = threadIdx.x, bid = blockIdx.x;
  size_t cbase = (size_t)bid * 8192;       // bid = b*256 + t
  const char* Xb = (const char*)(X + cbase);
  #pragma unroll
  for(int i=0;i<4;i++){
    int off = i*4096 + tid*16;
    int row = off >> 9;
    int P = (off >> 4) & 31;
    int L = (P & 16) | ((P & 15) ^ (row & 15));
    short8 v = *(const short8*)(Xb + (size_t)row*512 + L*16);
    *(short8*)((char*)lA + off) = v;
  }
  __syncthreads();
  int lane = tid & 63, wave = tid >> 6;
  int nlo = lane & 15, khi = lane >> 4;
  int cg0 = wave*4;

  f32x4 out[2][4];
  #pragma unroll
  for(int a=0;a<2;a++)
    #pragma unroll
    for(int q=0;q<4;q++) out[a][q] = {0.f,0.f,0.f,0.f};

  // mix chunk 0 (= h itself), W column 0
  {
    int wiA = nlo*224 + 0*32 + khi*8;
    short8 wh0 = *(const short8*)(WH + wiA);
    short8 wl0 = *(const short8*)(WL + wiA);
    short8 wh1 = *(const short8*)(WH + wiA + 16*224);
    short8 wl1 = *(const short8*)(WL + wiA + 16*224);
    #pragma unroll
    for(int nf=0;nf<4;nf++){
      short8 f = gath(lA, (wave<<6)+(nf<<4)+nlo, khi);
      out[0][nf]=MF(wh0,f,out[0][nf]); out[0][nf]=MF(wl0,f,out[0][nf]);
      out[1][nf]=MF(wh1,f,out[1][nf]); out[1][nf]=MF(wl1,f,out[1][nf]);
    }
  }

  for(int v=0; v<6; v++){
    const u16* bp = bpack + ((size_t)v << 16);
    f32x4 hacc[2][4];
    #pragma unroll
    for(int a=0;a<2;a++)
      #pragma unroll
      for(int q=0;q<4;q++) hacc[a][q] = {0.f,0.f,0.f,0.f};
    short8 pb[4] = {LB(0,0), LB(0,1), LB(0,2), LB(0,3)};
    #pragma unroll
    for(int ks=0;ks<8;ks++){
      short8 a[2];
      #pragma unroll
      for(int mf=0;mf<2;mf++){
        int row = mf*16 + nlo;
        int L = ks*4 + khi;
        int P = (L&16)|((L&15)^(row&15));
        a[mf] = *(const short8*)&lA[row*256 + P*8];
      }
      short8 qb[4];
      if(ks<7){
        #pragma unroll
        for(int nf=0;nf<4;nf++) qb[nf] = LB(ks+1,nf);
      }
      #pragma unroll
      for(int mf=0;mf<2;mf++)
        #pragma unroll
        for(int nf=0;nf<4;nf++)
          hacc[mf][nf] = MF(a[mf], pb[nf], hacc[mf][nf]);
      if(ks<7){
        #pragma unroll
        for(int nf=0;nf<4;nf++) pb[nf] = qb[nf];
      }
    }
    __syncthreads();   // previous chunk's lY gathers complete
    #pragma unroll
    for(int mf=0;mf<2;mf++)
      #pragma unroll
      for(int nf=0;nf<4;nf++)
        #pragma unroll
        for(int rr=0;rr<4;rr++){
          int row = mf*16 + khi*4 + rr;
          int col = (wave<<6) + (nf<<4) + nlo;
          int Lc = col >> 3;
          int P = (Lc&16)|((Lc&15)^(row&15));
          *(u16*)((char*)lY + row*512 + P*16 + (col&7)*2) = f2bf(hacc[mf][nf][rr]);
        }
    __syncthreads();
    // mix chunk v+1
    {
      int wiA = nlo*224 + (v+1)*32 + khi*8;
      short8 wh0 = *(const short8*)(WH + wiA);
      short8 wl0 = *(const short8*)(WL + wiA);
      short8 wh1 = *(const short8*)(WH + wiA + 16*224);
      short8 wl1 = *(const short8*)(WL + wiA + 16*224);
      #pragma unroll
      for(int nf=0;nf<4;nf++){
        short8 f = gath(lY, (wave<<6)+(nf<<4)+nlo, khi);
        out[0][nf]=MF(wh0,f,out[0][nf]); out[0][nf]=MF(wl0,f,out[0][nf]);
        out[1][nf]=MF(wh1,f,out[1][nf]); out[1][nf]=MF(wl1,f,out[1][nf]);
      }
    }
  }

  #pragma unroll
  for(int ot=0;ot<2;ot++)
    #pragma unroll
    for(int nf=0;nf<4;nf++)
      #pragma unroll
      for(int rr=0;rr<4;rr++){
        int o = ot*16 + khi*4 + rr;
        int n = (wave<<6) + (nf<<4) + nlo;
        float val = out[ot][nf][rr] + bm[o];
        size_t a = cbase + (size_t)o*256 + n;
        if(MODE==0){
          u16 hh = f2bf(val);
          mbh[a] = hh;
          mbl[a] = f2bf(val - bf2f(hh));
        } else {
          m[a] = val;
        }
      }
}
#undef LB
#undef MF

// ---------------- m [b][t][o][n] f32 -> dst [b][o][n][t] f32
__global__ __launch_bounds__(256) void k_tip(const float* __restrict__ m, float* __restrict__ dst){
  int tile = blockIdx.x & 15; int slice = blockIdx.x >> 4;
  int b = slice >> 5, o = slice & 31;
  int tn0 = (tile & 3) * 64, tt0 = (tile >> 2) * 64;
  __shared__ float l[64][65];
  int cc = threadIdx.x & 63, r0 = threadIdx.x >> 6;
  #pragma unroll
  for(int k=0;k<16;k++){ int r = r0 + 4*k;
    l[r][cc] = m[(((size_t)b*256 + (tt0+r))*32 + o)*256 + tn0 + cc];
  }
  __syncthreads();
  #pragma unroll
  for(int k=0;k<16;k++){ int r = r0 + 4*k;
    dst[(((size_t)b*32 + o)*256 + (tn0+r))*256 + tt0 + cc] = l[cc][r];
  }
}

extern "C" void kernel_launch(void* const* d_in, const int* in_sizes, int n_in,
                              void* d_out, int out_size, void* d_ws, size_t ws_size,
                              hipStream_t stream){
  (void)in_sizes; (void)n_in; (void)out_size;
  const float* x    = (const float*)d_in[0];
  const float* nv1  = (const float*)d_in[1];
  const float* nv2  = (const float*)d_in[2];
  const float* sup0 = (const float*)d_in[3];
  const float* sup1 = (const float*)d_in[4];
  const float* wf1 = (const float*)d_in[5];  const float* bf1v = (const float*)d_in[6];
  const float* wg1 = (const float*)d_in[7];  const float* bg1v = (const float*)d_in[8];
  const float* wf2 = (const float*)d_in[9];  const float* bf2v = (const float*)d_in[10];
  const float* wg2 = (const float*)d_in[11]; const float* bg2v = (const float*)d_in[12];
  const float* wm1 = (const float*)d_in[13]; const float* bm1 = (const float*)d_in[14];
  const float* wm2 = (const float*)d_in[15]; const float* bm2 = (const float*)d_in[16];
  float* out = (float*)d_out;
  char* ws = (char*)d_ws;
  const size_t MB = (size_t)1 << 20;

  u16*  badj  = (u16*)ws;                    // 384 KB
  u16*  badj2 = (u16*)(ws + 393216);         // 384 KB
  float* adp  = (float*)(ws + 786432);       // 256 KB
  u16*  whi   = (u16*)(ws + 1048576);        // 28 KB
  u16*  wlo   = (u16*)(ws + 1077248);        // 28 KB
  u16*  wcp   = (u16*)(ws + 1105920);        // 32 KB
  u16*  bpack = (u16*)(ws + 1179648);        // 768 KB, ends < 2 MB

  int tier = (ws_size >= 100*MB) ? 0 : 1;
  u16* h   = (u16*)(ws + 2*MB);
  u16* mbh = (u16*)(ws + 18*MB);
  u16* mbl = (u16*)(ws + 34*MB);
  u16* xT;
  float *m, *tmp = nullptr;
  if(tier==0){
    m  = (float*)(ws + 50*MB);
    xT = (u16*)(ws + 82*MB);
  } else {
    xT = mbh;                 // xT dead before fuse<0> writes mbh
    m  = out;
    tmp = (float*)(ws + 2*MB); // h+mbh regions, dead at tip time
  }

  k_adp<<<256,256,0,stream>>>(nv1, nv2, adp);
  k_badj<<<768,256,0,stream>>>(sup0, sup1, adp, badj);
  k_wprep<<<88,256,0,stream>>>(wm1, wm2, wf1, wg1, wf2, wg2, whi, wlo, wcp);
  k_asq<<<12,256,0,stream>>>(badj, sup0, sup1, adp, badj2);
  k_pack<<<192,256,0,stream>>>(badj, badj2, bpack);
  k_tin<<<2048,256,0,stream>>>(x, xT);

  // block 1
  k_cv<0><<<1024,256,0,stream>>>(xT, (const u16*)0, wcp, 0, 1, bf1v, bg1v, h);
  k_fuse<0><<<1024,256,0,stream>>>(h, bpack, whi, wlo, bm1, (float*)0, mbh, mbl);
  // block 2
  k_cv<1><<<1024,256,0,stream>>>(mbh, mbl, wcp, 1, 2, bf2v, bg2v, h);
  k_fuse<1><<<1024,256,0,stream>>>(h, bpack, whi+7168, wlo+7168, bm2, m, (u16*)0, (u16*)0);

  if(tier==0){
    k_tip<<<2048,256,0,stream>>>(m, out);
  } else {
    k_tip<<<2048,256,0,stream>>>(m, tmp);
    hipMemcpyAsync(out, tmp, (size_t)32*MB, hipMemcpyDeviceToDevice, stream);
  }
}

// Round 8
// 198.723 us; speedup vs baseline: 2.6811x; 1.2505x over previous
//
#include <hip/hip_runtime.h>
#include <hip/hip_bf16.h>
#include <stdint.h>

typedef unsigned short u16;
typedef __attribute__((ext_vector_type(8))) short short8;
typedef __attribute__((ext_vector_type(4))) float f32x4;

__device__ __forceinline__ float bf2f(u16 b){ union {unsigned u; float f;} v; v.u = ((unsigned)b)<<16; return v.f; }
__device__ __forceinline__ u16 f2bf(float f){ union {unsigned u; float f;} v; v.f = f; unsigned r = v.u + 0x7FFF + ((v.u>>16)&1); return (u16)(r>>16); }

// ---------------- adaptive adjacency
__global__ __launch_bounds__(256) void k_adp(const float* __restrict__ nv1, const float* __restrict__ nv2,
                                             float* __restrict__ adp){
  int row = blockIdx.x; int j = threadIdx.x;
  float s = 0.f;
  #pragma unroll
  for(int k=0;k<10;k++) s = fmaf(nv1[row*10+k], nv2[k*256+j], s);
  s = s > 0.f ? s : 0.f;
  float val = (s == 0.f) ? -1e10f : s;
  __shared__ float red[256];
  red[j] = val; __syncthreads();
  for(int off=128; off>0; off>>=1){ if(j<off) red[j] = fmaxf(red[j], red[j+off]); __syncthreads(); }
  float mx = red[0]; __syncthreads();
  float e = __expf(val - mx);
  red[j] = e; __syncthreads();
  for(int off=128; off>0; off>>=1){ if(j<off) red[j] += red[j+off]; __syncthreads(); }
  adp[row*256+j] = e / red[0];
}

// ---------------- badj[s][w][v] = src_s[v][w]
__global__ __launch_bounds__(256) void k_badj(const float* __restrict__ s0, const float* __restrict__ s1,
                                              const float* __restrict__ adp, u16* __restrict__ badj){
  int s = blockIdx.x >> 8; int w = blockIdx.x & 255; int v = threadIdx.x;
  const float* src = s==0 ? s0 : (s==1 ? s1 : adp);
  badj[(s<<16) + (w<<8) + v] = f2bf(src[v*256 + w]);
}

// ---------------- weight prep
__global__ __launch_bounds__(256) void k_wprep(const float* __restrict__ wm1, const float* __restrict__ wm2,
                                               const float* __restrict__ wf1, const float* __restrict__ wg1,
                                               const float* __restrict__ wf2, const float* __restrict__ wg2,
                                               u16* __restrict__ whi, u16* __restrict__ wlo,
                                               u16* __restrict__ wcp){
  int idx = blockIdx.x*256 + threadIdx.x;
  if(idx < 14336){
    float w = (idx < 7168) ? wm1[idx] : wm2[idx-7168];
    u16 hh = f2bf(w);
    whi[idx] = hh;
    wlo[idx] = f2bf(w - bf2f(hh));
  } else {
    int e = idx - 14336;
    int blk = e >> 12; int rem = e & 4095;
    int row = rem >> 6; int kk = rem & 63;
    int tap = kk >> 5; int i = kk & 31; int o = row & 31;
    const float* wsrc = blk ? (row<32 ? wf2 : wg2) : (row<32 ? wf1 : wg1);
    float w = wsrc[(o*32+i)*2 + tap];
    u16 hh = f2bf(w);
    wcp[blk*8192 + 0    + rem] = hh;
    wcp[blk*8192 + 4096 + rem] = f2bf(w - bf2f(hh));
  }
}

// ---------------- x [b][c][n][t] f32 -> xT [b][t][c][n] bf16
__global__ __launch_bounds__(256) void k_tin(const float* __restrict__ x, u16* __restrict__ xT){
  int tile = blockIdx.x & 15; int slice = blockIdx.x >> 4;
  int b = slice >> 5, c = slice & 31;
  int tn0 = (tile & 3) * 64;
  int tt0 = (tile >> 2) * 64;
  const float* src = x + (size_t)slice*65536;
  __shared__ float l[64][65];
  int cc = threadIdx.x & 63, r0 = threadIdx.x >> 6;
  #pragma unroll
  for(int k=0;k<16;k++){ int r = r0 + 4*k;
    l[r][cc] = src[(size_t)(tn0 + r)*256 + tt0 + cc];
  }
  __syncthreads();
  #pragma unroll
  for(int k=0;k<16;k++){ int r = r0 + 4*k;
    xT[(((size_t)b*256 + (tt0+r))*32 + c)*256 + tn0 + cc] = f2bf(l[cc][r]);
  }
}

// ---------------- badj2[s] = badj[s] . badj[s]  (= (A^2)^T stored [w][v])
__global__ __launch_bounds__(256) void k_asq(const u16* __restrict__ badj,
                                             const float* __restrict__ s0, const float* __restrict__ s1,
                                             const float* __restrict__ adp, u16* __restrict__ badj2){
  __shared__ __align__(16) u16 lds[16384];
  int tid = threadIdx.x, bid = blockIdx.x;
  int s = bid >> 2, rt = bid & 3;
  int w0 = rt << 6;
  const u16* T = badj + (s<<16);
  const float* S = s==0 ? s0 : (s==1 ? s1 : adp);
  #pragma unroll
  for(int i=0;i<8;i++){
    int off = i*4096 + tid*16;
    int row = off >> 9;
    int P = (off >> 4) & 31;
    int L = (P & 16) | ((P & 15) ^ (row & 15));
    short8 v = *(const short8*)((const char*)T + (size_t)(w0 + row)*512 + L*16);
    *(short8*)((char*)lds + off) = v;
  }
  __syncthreads();
  int lane = tid & 63, wave = tid >> 6;
  int wr = (wave >> 1) << 5, wc = (wave & 1) << 7;
  f32x4 acc[2][8];
  #pragma unroll
  for(int a=0;a<2;a++)
    #pragma unroll
    for(int q=0;q<8;q++) acc[a][q] = {0.f,0.f,0.f,0.f};
  for(int ks=0; ks<8; ks++){
    short8 afr[2], bfr[8];
    #pragma unroll
    for(int mf=0; mf<2; mf++){
      int row = wr + mf*16 + (lane & 15);
      int L = ks*4 + (lane >> 4);
      int P = (L & 16) | ((L & 15) ^ (row & 15));
      afr[mf] = *(const short8*)&lds[row*256 + P*8];
    }
    #pragma unroll
    for(int nf=0; nf<8; nf++){
      int col = wc + nf*16 + (lane & 15);
      const float* src = S + (size_t)col*256 + ks*32 + (lane>>4)*8;
      #pragma unroll
      for(int jj=0;jj<8;jj++) bfr[nf][jj] = (short)f2bf(src[jj]);
    }
    #pragma unroll
    for(int mf=0;mf<2;mf++)
      #pragma unroll
      for(int nf=0;nf<8;nf++)
        acc[mf][nf] = __builtin_amdgcn_mfma_f32_16x16x32_bf16(afr[mf], bfr[nf], acc[mf][nf], 0,0,0);
  }
  u16* D = badj2 + (s<<16) + (size_t)w0*256;
  #pragma unroll
  for(int mf=0;mf<2;mf++)
    #pragma unroll
    for(int nf=0;nf<8;nf++)
      #pragma unroll
      for(int rr=0;rr<4;rr++){
        int row = wr + mf*16 + (lane>>4)*4 + rr;
        int col = wc + nf*16 + (lane&15);
        D[row*256 + col] = f2bf(acc[mf][nf][rr]);
      }
}

// ---------------- pack adjacency into MFMA B-fragment order (49152 threads -> grid 192)
__global__ __launch_bounds__(256) void k_pack(const u16* __restrict__ badj, const u16* __restrict__ badj2,
                                              u16* __restrict__ bpack){
  int t = blockIdx.x*256 + threadIdx.x;      // < 49152
  int lane = t & 63; int cg = (t>>6)&15; int ks = (t>>10)&7; int mat = (t>>13)&1; int s = t>>14;
  const u16* src = (mat ? badj2 : badj) + (s<<16) + (cg*16 + (lane&15))*256 + ks*32 + (lane>>4)*8;
  short8 v = *(const short8*)src;
  *(short8*)(bpack + (size_t)t*8) = v;
}

// ---------------- MFMA gated conv (+bias, sigmoid gate)
template<int HILO>
__global__ __launch_bounds__(256) void k_cv(const u16* __restrict__ X0, const u16* __restrict__ X1,
                                            const u16* __restrict__ wcp, int blk, int dil,
                                            const float* __restrict__ bfv, const float* __restrict__ bgv,
                                            u16* __restrict__ outh){
  __shared__ __align__(16) u16 pl[(1+HILO)*2*8192];
  const int NPART = 1+HILO;
  int tid = threadIdx.x, bid = blockIdx.x;
  int b = bid >> 8, t = bid & 255;
  size_t base_cur = ((size_t)(b*256 + t))*8192;
  const u16* Xs[2] = {X0, X1};
  #pragma unroll
  for(int part=0; part<NPART; part++){
    #pragma unroll
    for(int tap=0; tap<2; tap++){
      bool valid = (tap==1) || (t >= dil);
      const u16* src = Xs[part] + base_cur - (tap==0 ? (size_t)dil*8192 : 0);
      char* pb = (char*)pl + (tap*NPART + part)*16384;
      #pragma unroll
      for(int it=0; it<4; it++){
        int off = it*4096 + tid*16;
        int c = off >> 9;
        int byte = off & 511;
        short8 v = {0,0,0,0,0,0,0,0};
        if(valid) v = *(const short8*)(src + (off>>1));
        *(short8*)(pb + c*512 + (byte ^ ((c&24)<<2))) = v;
      }
    }
  }
  int lane = tid & 63, wave = tid >> 6;
  const u16* wb = wcp + blk*8192;
  short8 wfr[4][2][2];
  #pragma unroll
  for(int ot=0;ot<4;ot++)
    #pragma unroll
    for(int ks=0;ks<2;ks++)
      #pragma unroll
      for(int p=0;p<2;p++)
        wfr[ot][ks][p] = *(const short8*)(wb + p*4096 + (ot*16 + (lane&15))*64 + ks*32 + (lane>>4)*8);
  __syncthreads();

  f32x4 acc[4][4];
  #pragma unroll
  for(int a=0;a<4;a++)
    #pragma unroll
    for(int q=0;q<4;q++) acc[a][q] = {0.f,0.f,0.f,0.f};
  int nbase = wave << 6;
  #pragma unroll
  for(int nf=0; nf<4; nf++){
    int n = nbase + nf*16 + (lane & 15);
    #pragma unroll
    for(int ks=0; ks<2; ks++){
      short8 xv[NPART];
      #pragma unroll
      for(int p=0;p<NPART;p++){
        char* pb = (char*)pl + (ks*NPART + p)*16384;
        short8 v;
        #pragma unroll
        for(int jj=0;jj<8;jj++){
          int c = ((lane>>4)<<3) + jj;
          v[jj] = *(const short*)(pb + c*512 + ((n*2) ^ ((c&24)<<2)));
        }
        xv[p] = v;
      }
      #pragma unroll
      for(int ot=0; ot<4; ot++){
        acc[ot][nf] = __builtin_amdgcn_mfma_f32_16x16x32_bf16(wfr[ot][ks][0], xv[0], acc[ot][nf], 0,0,0);
        acc[ot][nf] = __builtin_amdgcn_mfma_f32_16x16x32_bf16(wfr[ot][ks][1], xv[0], acc[ot][nf], 0,0,0);
        if(HILO)
          acc[ot][nf] = __builtin_amdgcn_mfma_f32_16x16x32_bf16(wfr[ot][ks][0], xv[HILO], acc[ot][nf], 0,0,0);
      }
    }
  }
  u16* ob = outh + base_cur;
  #pragma unroll
  for(int ot=0; ot<2; ot++)
    #pragma unroll
    for(int nf=0; nf<4; nf++)
      #pragma unroll
      for(int rr=0; rr<4; rr++){
        int o = ot*16 + (lane>>4)*4 + rr;
        int n = nbase + nf*16 + (lane&15);
        float fv = acc[ot][nf][rr] + bfv[o];
        float gv = acc[ot+2][nf][rr] + bgv[o];
        ob[(size_t)o*256 + n] = f2bf(fv / (1.f + __expf(-gv)));
      }
}

// ---------------- fused hop+mix v2: per (b,t,col-half) block, barrier-free main loop.
// lA: h tile [32 c][256 v] row-XOR swizzle (shared). lY: per-wave private [32 c][32 lc] slice,
// 128B rows, quadrant-rotated: addr = wv*4096 + c*128 + ((lc*2 + (c>>3)*32)&127).
// Hop: 2mf x 2nf, 2-deep B prefetch from packed adjacency. Mix: gather own slice, hi/lo W MFMAs.
#define LB(KS,FC) (*(const short8*)(bp + ((((KS)*16) + cg0 + (FC))<<9) + (lane<<3)))
#define MF(A,B,C) __builtin_amdgcn_mfma_f32_16x16x32_bf16((A),(B),(C),0,0,0)
#define AF(MFI,KS) (*(const short8*)&lA[(MFI*16 + nlo)*256 + (((KS*4+khi)&16)|(((KS*4+khi)&15)^((MFI*16+nlo)&15)))*8])
template<int MODE>
__global__ __launch_bounds__(256, 4) void k_fuse(const u16* __restrict__ X,
                                                 const u16* __restrict__ bpack,
                                                 const u16* __restrict__ WH, const u16* __restrict__ WL,
                                                 const float* __restrict__ bm,
                                                 float* __restrict__ m, u16* __restrict__ mbh, u16* __restrict__ mbl){
  __shared__ __align__(16) u16 lA[8192];   // 16 KB
  __shared__ __align__(16) u16 lY[8192];   // 16 KB = 4 x 4KB wave-private slices
  int tid = threadIdx.x, bid = blockIdx.x;
  int ch = bid & 1;
  size_t cbase = (size_t)(bid >> 1) * 8192;
  const char* Xb = (const char*)(X + cbase);
  #pragma unroll
  for(int i=0;i<4;i++){
    int off = i*4096 + tid*16;
    int row = off >> 9;
    int P = (off >> 4) & 31;
    int L = (P & 16) | ((P & 15) ^ (row & 15));
    short8 v = *(const short8*)(Xb + (size_t)row*512 + L*16);
    *(short8*)((char*)lA + off) = v;
  }
  __syncthreads();
  int lane = tid & 63, wave = tid >> 6;
  int nlo = lane & 15, khi = lane >> 4;
  int cg0 = ch*8 + wave*2;                    // wave's 2 col-groups (32 cols)
  char* myY = (char*)lY + wave*4096;

  f32x4 out00={0,0,0,0}, out01=out00, out10=out00, out11=out00;   // [ot][nf]

  // mix chunk 0 (= h itself) from lA
  {
    int wiA = nlo*224 + khi*8;
    short8 wh0 = *(const short8*)(WH + wiA);
    short8 wl0 = *(const short8*)(WL + wiA);
    short8 wh1 = *(const short8*)(WH + wiA + 3584);
    short8 wl1 = *(const short8*)(WL + wiA + 3584);
    #pragma unroll
    for(int nf=0;nf<2;nf++){
      int n = (ch*8 + wave*2 + nf)*16 + nlo;
      short8 f; int Lc = n >> 3; int bb = (n & 7)*2;
      #pragma unroll
      for(int j=0;j<8;j++){
        int c = khi*8 + j;
        int P = (Lc & 16) | ((Lc & 15) ^ (c & 15));
        f[j] = *(const u16*)((const char*)lA + c*512 + P*16 + bb);
      }
      if(nf==0){ out00=MF(wh0,f,out00); out00=MF(wl0,f,out00); out10=MF(wh1,f,out10); out10=MF(wl1,f,out10); }
      else     { out01=MF(wh0,f,out01); out01=MF(wl0,f,out01); out11=MF(wh1,f,out11); out11=MF(wl1,f,out11); }
    }
  }

  #pragma unroll
  for(int v=0; v<6; v++){
    const u16* bp = bpack + ((size_t)v << 16);
    f32x4 h00={0,0,0,0}, h01=h00, h10=h00, h11=h00;   // [mf][nf]
    short8 p0 = LB(0,0), p1 = LB(0,1);
    short8 q0 = LB(1,0), q1 = LB(1,1);
    #pragma unroll
    for(int ks=0; ks<8; ks++){
      short8 r0, r1;
      if(ks < 6){ r0 = LB(ks+2,0); r1 = LB(ks+2,1); }
      short8 a0 = AF(0,ks), a1 = AF(1,ks);
      h00 = MF(a0, p0, h00);
      h01 = MF(a0, p1, h01);
      h10 = MF(a1, p0, h10);
      h11 = MF(a1, p1, h11);
      p0 = q0; p1 = q1;
      if(ks < 6){ q0 = r0; q1 = r1; }
    }
    // epilogue -> wave-private lY slice (no barrier needed)
    #pragma unroll
    for(int mf=0;mf<2;mf++)
      #pragma unroll
      for(int nf=0;nf<2;nf++)
        #pragma unroll
        for(int rr=0;rr<4;rr++){
          f32x4 hv = mf==0 ? (nf==0?h00:h01) : (nf==0?h10:h11);
          int c = mf*16 + khi*4 + rr;
          int lc = nf*16 + nlo;
          *(u16*)(myY + c*128 + ((lc*2 + (c>>3)*32)&127)) = f2bf(hv[rr]);
        }
    // mix chunk v+1 from own slice
    {
      int wiA = nlo*224 + (v+1)*32 + khi*8;
      short8 wh0 = *(const short8*)(WH + wiA);
      short8 wl0 = *(const short8*)(WL + wiA);
      short8 wh1 = *(const short8*)(WH + wiA + 3584);
      short8 wl1 = *(const short8*)(WL + wiA + 3584);
      int rbase = (nlo*2 + khi*32) & 127;     // (c>>3)==khi constant per lane
      #pragma unroll
      for(int nf=0;nf<2;nf++){
        short8 f;
        #pragma unroll
        for(int j=0;j<8;j++){
          int c = khi*8 + j;
          f[j] = *(const u16*)(myY + c*128 + ((rbase + nf*32)&127));
        }
        if(nf==0){ out00=MF(wh0,f,out00); out00=MF(wl0,f,out00); out10=MF(wh1,f,out10); out10=MF(wl1,f,out10); }
        else     { out01=MF(wh0,f,out01); out01=MF(wl0,f,out01); out11=MF(wh1,f,out11); out11=MF(wl1,f,out11); }
      }
    }
  }

  #pragma unroll
  for(int ot=0;ot<2;ot++)
    #pragma unroll
    for(int nf=0;nf<2;nf++)
      #pragma unroll
      for(int rr=0;rr<4;rr++){
        f32x4 ov = ot==0 ? (nf==0?out00:out01) : (nf==0?out10:out11);
        int o = ot*16 + khi*4 + rr;
        int n = (ch*8 + wave*2 + nf)*16 + nlo;
        float val = ov[rr] + bm[o];
        size_t a = cbase + (size_t)o*256 + n;
        if(MODE==0){
          u16 hh = f2bf(val);
          mbh[a] = hh;
          mbl[a] = f2bf(val - bf2f(hh));
        } else {
          m[a] = val;
        }
      }
}
#undef LB
#undef MF
#undef AF

// ---------------- m [b][t][o][n] f32 -> dst [b][o][n][t] f32
__global__ __launch_bounds__(256) void k_tip(const float* __restrict__ m, float* __restrict__ dst){
  int tile = blockIdx.x & 15; int slice = blockIdx.x >> 4;
  int b = slice >> 5, o = slice & 31;
  int tn0 = (tile & 3) * 64, tt0 = (tile >> 2) * 64;
  __shared__ float l[64][65];
  int cc = threadIdx.x & 63, r0 = threadIdx.x >> 6;
  #pragma unroll
  for(int k=0;k<16;k++){ int r = r0 + 4*k;
    l[r][cc] = m[(((size_t)b*256 + (tt0+r))*32 + o)*256 + tn0 + cc];
  }
  __syncthreads();
  #pragma unroll
  for(int k=0;k<16;k++){ int r = r0 + 4*k;
    dst[(((size_t)b*32 + o)*256 + (tn0+r))*256 + tt0 + cc] = l[cc][r];
  }
}

extern "C" void kernel_launch(void* const* d_in, const int* in_sizes, int n_in,
                              void* d_out, int out_size, void* d_ws, size_t ws_size,
                              hipStream_t stream){
  (void)in_sizes; (void)n_in; (void)out_size;
  const float* x    = (const float*)d_in[0];
  const float* nv1  = (const float*)d_in[1];
  const float* nv2  = (const float*)d_in[2];
  const float* sup0 = (const float*)d_in[3];
  const float* sup1 = (const float*)d_in[4];
  const float* wf1 = (const float*)d_in[5];  const float* bf1v = (const float*)d_in[6];
  const float* wg1 = (const float*)d_in[7];  const float* bg1v = (const float*)d_in[8];
  const float* wf2 = (const float*)d_in[9];  const float* bf2v = (const float*)d_in[10];
  const float* wg2 = (const float*)d_in[11]; const float* bg2v = (const float*)d_in[12];
  const float* wm1 = (const float*)d_in[13]; const float* bm1 = (const float*)d_in[14];
  const float* wm2 = (const float*)d_in[15]; const float* bm2 = (const float*)d_in[16];
  float* out = (float*)d_out;
  char* ws = (char*)d_ws;
  const size_t MB = (size_t)1 << 20;

  u16*  badj  = (u16*)ws;                    // 384 KB
  u16*  badj2 = (u16*)(ws + 393216);         // 384 KB
  float* adp  = (float*)(ws + 786432);       // 256 KB
  u16*  whi   = (u16*)(ws + 1048576);        // 28 KB
  u16*  wlo   = (u16*)(ws + 1077248);        // 28 KB
  u16*  wcp   = (u16*)(ws + 1105920);        // 32 KB
  u16*  bpack = (u16*)(ws + 1179648);        // 768 KB, ends < 2 MB

  int tier = (ws_size >= 100*MB) ? 0 : 1;
  u16* h   = (u16*)(ws + 2*MB);
  u16* mbh = (u16*)(ws + 18*MB);
  u16* mbl = (u16*)(ws + 34*MB);
  u16* xT;
  float *m, *tmp = nullptr;
  if(tier==0){
    m  = (float*)(ws + 50*MB);
    xT = (u16*)(ws + 82*MB);
  } else {
    xT = mbh;                 // xT dead before fuse<0> writes mbh
    m  = out;
    tmp = (float*)(ws + 2*MB);
  }

  k_adp<<<256,256,0,stream>>>(nv1, nv2, adp);
  k_badj<<<768,256,0,stream>>>(sup0, sup1, adp, badj);
  k_wprep<<<88,256,0,stream>>>(wm1, wm2, wf1, wg1, wf2, wg2, whi, wlo, wcp);
  k_asq<<<12,256,0,stream>>>(badj, sup0, sup1, adp, badj2);
  k_pack<<<192,256,0,stream>>>(badj, badj2, bpack);
  k_tin<<<2048,256,0,stream>>>(x, xT);

  // block 1
  k_cv<0><<<1024,256,0,stream>>>(xT, (const u16*)0, wcp, 0, 1, bf1v, bg1v, h);
  k_fuse<0><<<2048,256,0,stream>>>(h, bpack, whi, wlo, bm1, (float*)0, mbh, mbl);
  // block 2
  k_cv<1><<<1024,256,0,stream>>>(mbh, mbl, wcp, 1, 2, bf2v, bg2v, h);
  k_fuse<1><<<2048,256,0,stream>>>(h, bpack, whi+7168, wlo+7168, bm2, m, (u16*)0, (u16*)0);

  if(tier==0){
    k_tip<<<2048,256,0,stream>>>(m, out);
  } else {
    k_tip<<<2048,256,0,stream>>>(m, tmp);
    hipMemcpyAsync(out, tmp, (size_t)32*MB, hipMemcpyDeviceToDevice, stream);
  }
}

// Round 9
// 190.826 us; speedup vs baseline: 2.7921x; 1.0414x over previous
//
#include <hip/hip_runtime.h>
#include <hip/hip_bf16.h>
#include <stdint.h>

typedef unsigned short u16;
typedef __attribute__((ext_vector_type(8))) short short8;
typedef __attribute__((ext_vector_type(4))) short short4a;
typedef __attribute__((ext_vector_type(4))) float f32x4;

__device__ __forceinline__ float bf2f(u16 b){ union {unsigned u; float f;} v; v.u = ((unsigned)b)<<16; return v.f; }
__device__ __forceinline__ u16 f2bf(float f){ union {unsigned u; float f;} v; v.f = f; unsigned r = v.u + 0x7FFF + ((v.u>>16)&1); return (u16)(r>>16); }

// ---------------- adaptive adjacency
__global__ __launch_bounds__(256) void k_adp(const float* __restrict__ nv1, const float* __restrict__ nv2,
                                             float* __restrict__ adp){
  int row = blockIdx.x; int j = threadIdx.x;
  float s = 0.f;
  #pragma unroll
  for(int k=0;k<10;k++) s = fmaf(nv1[row*10+k], nv2[k*256+j], s);
  s = s > 0.f ? s : 0.f;
  float val = (s == 0.f) ? -1e10f : s;
  __shared__ float red[256];
  red[j] = val; __syncthreads();
  for(int off=128; off>0; off>>=1){ if(j<off) red[j] = fmaxf(red[j], red[j+off]); __syncthreads(); }
  float mx = red[0]; __syncthreads();
  float e = __expf(val - mx);
  red[j] = e; __syncthreads();
  for(int off=128; off>0; off>>=1){ if(j<off) red[j] += red[j+off]; __syncthreads(); }
  adp[row*256+j] = e / red[0];
}

// ---------------- badj[s][w][v] = src_s[v][w]
__global__ __launch_bounds__(256) void k_badj(const float* __restrict__ s0, const float* __restrict__ s1,
                                              const float* __restrict__ adp, u16* __restrict__ badj){
  int s = blockIdx.x >> 8; int w = blockIdx.x & 255; int v = threadIdx.x;
  const float* src = s==0 ? s0 : (s==1 ? s1 : adp);
  badj[(s<<16) + (w<<8) + v] = f2bf(src[v*256 + w]);
}

// ---------------- weight prep
__global__ __launch_bounds__(256) void k_wprep(const float* __restrict__ wm1, const float* __restrict__ wm2,
                                               const float* __restrict__ wf1, const float* __restrict__ wg1,
                                               const float* __restrict__ wf2, const float* __restrict__ wg2,
                                               u16* __restrict__ whi, u16* __restrict__ wlo,
                                               u16* __restrict__ wcp){
  int idx = blockIdx.x*256 + threadIdx.x;
  if(idx < 14336){
    float w = (idx < 7168) ? wm1[idx] : wm2[idx-7168];
    u16 hh = f2bf(w);
    whi[idx] = hh;
    wlo[idx] = f2bf(w - bf2f(hh));
  } else {
    int e = idx - 14336;
    int blk = e >> 12; int rem = e & 4095;
    int row = rem >> 6; int kk = rem & 63;
    int tap = kk >> 5; int i = kk & 31; int o = row & 31;
    const float* wsrc = blk ? (row<32 ? wf2 : wg2) : (row<32 ? wf1 : wg1);
    float w = wsrc[(o*32+i)*2 + tap];
    u16 hh = f2bf(w);
    wcp[blk*8192 + 0    + rem] = hh;
    wcp[blk*8192 + 4096 + rem] = f2bf(w - bf2f(hh));
  }
}

// ---------------- x [b][c][n][t] f32 -> xT [b][t][c][n] bf16
__global__ __launch_bounds__(256) void k_tin(const float* __restrict__ x, u16* __restrict__ xT){
  int tile = blockIdx.x & 15; int slice = blockIdx.x >> 4;
  int b = slice >> 5, c = slice & 31;
  int tn0 = (tile & 3) * 64;
  int tt0 = (tile >> 2) * 64;
  const float* src = x + (size_t)slice*65536;
  __shared__ float l[64][65];
  int cc = threadIdx.x & 63, r0 = threadIdx.x >> 6;
  #pragma unroll
  for(int k=0;k<16;k++){ int r = r0 + 4*k;
    l[r][cc] = src[(size_t)(tn0 + r)*256 + tt0 + cc];
  }
  __syncthreads();
  #pragma unroll
  for(int k=0;k<16;k++){ int r = r0 + 4*k;
    xT[(((size_t)b*256 + (tt0+r))*32 + c)*256 + tn0 + cc] = f2bf(l[cc][r]);
  }
}

// ---------------- badj2[s] = badj[s] . badj[s]  (= (A^2)^T stored [w][v])
__global__ __launch_bounds__(256) void k_asq(const u16* __restrict__ badj,
                                             const float* __restrict__ s0, const float* __restrict__ s1,
                                             const float* __restrict__ adp, u16* __restrict__ badj2){
  __shared__ __align__(16) u16 lds[16384];
  int tid = threadIdx.x, bid = blockIdx.x;
  int s = bid >> 2, rt = bid & 3;
  int w0 = rt << 6;
  const u16* T = badj + (s<<16);
  const float* S = s==0 ? s0 : (s==1 ? s1 : adp);
  #pragma unroll
  for(int i=0;i<8;i++){
    int off = i*4096 + tid*16;
    int row = off >> 9;
    int P = (off >> 4) & 31;
    int L = (P & 16) | ((P & 15) ^ (row & 15));
    short8 v = *(const short8*)((const char*)T + (size_t)(w0 + row)*512 + L*16);
    *(short8*)((char*)lds + off) = v;
  }
  __syncthreads();
  int lane = tid & 63, wave = tid >> 6;
  int wr = (wave >> 1) << 5, wc = (wave & 1) << 7;
  f32x4 acc[2][8];
  #pragma unroll
  for(int a=0;a<2;a++)
    #pragma unroll
    for(int q=0;q<8;q++) acc[a][q] = {0.f,0.f,0.f,0.f};
  for(int ks=0; ks<8; ks++){
    short8 afr[2], bfr[8];
    #pragma unroll
    for(int mf=0; mf<2; mf++){
      int row = wr + mf*16 + (lane & 15);
      int L = ks*4 + (lane >> 4);
      int P = (L & 16) | ((L & 15) ^ (row & 15));
      afr[mf] = *(const short8*)&lds[row*256 + P*8];
    }
    #pragma unroll
    for(int nf=0; nf<8; nf++){
      int col = wc + nf*16 + (lane & 15);
      const float* src = S + (size_t)col*256 + ks*32 + (lane>>4)*8;
      #pragma unroll
      for(int jj=0;jj<8;jj++) bfr[nf][jj] = (short)f2bf(src[jj]);
    }
    #pragma unroll
    for(int mf=0;mf<2;mf++)
      #pragma unroll
      for(int nf=0;nf<8;nf++)
        acc[mf][nf] = __builtin_amdgcn_mfma_f32_16x16x32_bf16(afr[mf], bfr[nf], acc[mf][nf], 0,0,0);
  }
  u16* D = badj2 + (s<<16) + (size_t)w0*256;
  #pragma unroll
  for(int mf=0;mf<2;mf++)
    #pragma unroll
    for(int nf=0;nf<8;nf++)
      #pragma unroll
      for(int rr=0;rr<4;rr++){
        int row = wr + mf*16 + (lane>>4)*4 + rr;
        int col = wc + nf*16 + (lane&15);
        D[row*256 + col] = f2bf(acc[mf][nf][rr]);
      }
}

// ---------------- pack adjacency into MFMA B-fragment order (49152 threads -> grid 192)
__global__ __launch_bounds__(256) void k_pack(const u16* __restrict__ badj, const u16* __restrict__ badj2,
                                              u16* __restrict__ bpack){
  int t = blockIdx.x*256 + threadIdx.x;      // < 49152
  int lane = t & 63; int cg = (t>>6)&15; int ks = (t>>10)&7; int mat = (t>>13)&1; int s = t>>14;
  const u16* src = (mat ? badj2 : badj) + (s<<16) + (cg*16 + (lane&15))*256 + ks*32 + (lane>>4)*8;
  short8 v = *(const short8*)src;
  *(short8*)(bpack + (size_t)t*8) = v;
}

// ---------------- MFMA gated conv (+bias, sigmoid gate)
template<int HILO>
__global__ __launch_bounds__(256) void k_cv(const u16* __restrict__ X0, const u16* __restrict__ X1,
                                            const u16* __restrict__ wcp, int blk, int dil,
                                            const float* __restrict__ bfv, const float* __restrict__ bgv,
                                            u16* __restrict__ outh){
  __shared__ __align__(16) u16 pl[(1+HILO)*2*8192];
  const int NPART = 1+HILO;
  int tid = threadIdx.x, bid = blockIdx.x;
  int b = bid >> 8, t = bid & 255;
  size_t base_cur = ((size_t)(b*256 + t))*8192;
  const u16* Xs[2] = {X0, X1};
  #pragma unroll
  for(int part=0; part<NPART; part++){
    #pragma unroll
    for(int tap=0; tap<2; tap++){
      bool valid = (tap==1) || (t >= dil);
      const u16* src = Xs[part] + base_cur - (tap==0 ? (size_t)dil*8192 : 0);
      char* pb = (char*)pl + (tap*NPART + part)*16384;
      #pragma unroll
      for(int it=0; it<4; it++){
        int off = it*4096 + tid*16;
        int c = off >> 9;
        int byte = off & 511;
        short8 v = {0,0,0,0,0,0,0,0};
        if(valid) v = *(const short8*)(src + (off>>1));
        *(short8*)(pb + c*512 + (byte ^ ((c&24)<<2))) = v;
      }
    }
  }
  int lane = tid & 63, wave = tid >> 6;
  const u16* wb = wcp + blk*8192;
  short8 wfr[4][2][2];
  #pragma unroll
  for(int ot=0;ot<4;ot++)
    #pragma unroll
    for(int ks=0;ks<2;ks++)
      #pragma unroll
      for(int p=0;p<2;p++)
        wfr[ot][ks][p] = *(const short8*)(wb + p*4096 + (ot*16 + (lane&15))*64 + ks*32 + (lane>>4)*8);
  __syncthreads();

  f32x4 acc[4][4];
  #pragma unroll
  for(int a=0;a<4;a++)
    #pragma unroll
    for(int q=0;q<4;q++) acc[a][q] = {0.f,0.f,0.f,0.f};
  int nbase = wave << 6;
  #pragma unroll
  for(int nf=0; nf<4; nf++){
    int n = nbase + nf*16 + (lane & 15);
    #pragma unroll
    for(int ks=0; ks<2; ks++){
      short8 xv[NPART];
      #pragma unroll
      for(int p=0;p<NPART;p++){
        char* pb = (char*)pl + (ks*NPART + p)*16384;
        short8 v;
        #pragma unroll
        for(int jj=0;jj<8;jj++){
          int c = ((lane>>4)<<3) + jj;
          v[jj] = *(const short*)(pb + c*512 + ((n*2) ^ ((c&24)<<2)));
        }
        xv[p] = v;
      }
      #pragma unroll
      for(int ot=0; ot<4; ot++){
        acc[ot][nf] = __builtin_amdgcn_mfma_f32_16x16x32_bf16(wfr[ot][ks][0], xv[0], acc[ot][nf], 0,0,0);
        acc[ot][nf] = __builtin_amdgcn_mfma_f32_16x16x32_bf16(wfr[ot][ks][1], xv[0], acc[ot][nf], 0,0,0);
        if(HILO)
          acc[ot][nf] = __builtin_amdgcn_mfma_f32_16x16x32_bf16(wfr[ot][ks][0], xv[HILO], acc[ot][nf], 0,0,0);
      }
    }
  }
  u16* ob = outh + base_cur;
  #pragma unroll
  for(int ot=0; ot<2; ot++)
    #pragma unroll
    for(int nf=0; nf<4; nf++)
      #pragma unroll
      for(int rr=0; rr<4; rr++){
        int o = ot*16 + (lane>>4)*4 + rr;
        int n = nbase + nf*16 + (lane&15);
        float fv = acc[ot][nf][rr] + bfv[o];
        float gv = acc[ot+2][nf][rr] + bgv[o];
        ob[(size_t)o*256 + n] = f2bf(fv / (1.f + __expf(-gv)));
      }
}

// ---------------- fused hop+mix v3: per (b,t,col-half) block, barrier-free main loop.
// lA: h tile [32 c][256 v], row-XOR slot swizzle (shared).
// lYT: per-wave private TRANSPOSED slice [32 n][32 c], 72B-padded rows:
//   addr = wave*2304 + n_local*72 + c*2.  Epilogue: 1 ds_write_b64 per (mf,nf).
//   Mix gather: 2 ds_read_b64 per nf (contiguous c). Both patterns bank-minimal.
#define LB(KS,FC) (*(const short8*)(bp + ((((KS)*16) + cg0 + (FC))<<9) + (lane<<3)))
#define MF(A,B,C) __builtin_amdgcn_mfma_f32_16x16x32_bf16((A),(B),(C),0,0,0)
#define AF(MFI,KS) (*(const short8*)&lA[(MFI*16 + nlo)*256 + (((KS*4+khi)&16)|(((KS*4+khi)&15)^((MFI*16+nlo)&15)))*8])
template<int MODE>
__global__ __launch_bounds__(256, 5) void k_fuse(const u16* __restrict__ X,
                                                 const u16* __restrict__ bpack,
                                                 const u16* __restrict__ WH, const u16* __restrict__ WL,
                                                 const float* __restrict__ bm,
                                                 float* __restrict__ m, u16* __restrict__ mbh, u16* __restrict__ mbl){
  __shared__ __align__(16) u16 lA[8192];     // 16 KB
  __shared__ __align__(16) char lYT[9216];   // 4 waves x 32 n x 72 B
  int tid = threadIdx.x, bid = blockIdx.x;
  int ch = bid & 1;
  size_t cbase = (size_t)(bid >> 1) * 8192;
  const char* Xb = (const char*)(X + cbase);
  #pragma unroll
  for(int i=0;i<4;i++){
    int off = i*4096 + tid*16;
    int row = off >> 9;
    int P = (off >> 4) & 31;
    int L = (P & 16) | ((P & 15) ^ (row & 15));
    short8 v = *(const short8*)(Xb + (size_t)row*512 + L*16);
    *(short8*)((char*)lA + off) = v;
  }
  __syncthreads();
  int lane = tid & 63, wave = tid >> 6;
  int nlo = lane & 15, khi = lane >> 4;
  int cg0 = ch*8 + wave*2;                    // wave's 2 col-groups (32 cols)
  char* myY = lYT + wave*2304;

  f32x4 out00={0,0,0,0}, out01=out00, out10=out00, out11=out00;   // [ot][nf]

  // mix chunk 0 (= h itself) from lA (scalar gather, once per block)
  {
    int wiA = nlo*224 + khi*8;
    short8 wh0 = *(const short8*)(WH + wiA);
    short8 wl0 = *(const short8*)(WL + wiA);
    short8 wh1 = *(const short8*)(WH + wiA + 3584);
    short8 wl1 = *(const short8*)(WL + wiA + 3584);
    #pragma unroll
    for(int nf=0;nf<2;nf++){
      int n = (ch*8 + wave*2 + nf)*16 + nlo;
      short8 f; int Lc = n >> 3; int bb = (n & 7)*2;
      #pragma unroll
      for(int j=0;j<8;j++){
        int c = khi*8 + j;
        int P = (Lc & 16) | ((Lc & 15) ^ (c & 15));
        f[j] = *(const u16*)((const char*)lA + c*512 + P*16 + bb);
      }
      if(nf==0){ out00=MF(wh0,f,out00); out00=MF(wl0,f,out00); out10=MF(wh1,f,out10); out10=MF(wl1,f,out10); }
      else     { out01=MF(wh0,f,out01); out01=MF(wl0,f,out01); out11=MF(wh1,f,out11); out11=MF(wl1,f,out11); }
    }
  }

  #pragma unroll
  for(int v=0; v<6; v++){
    const u16* bp = bpack + ((size_t)v << 16);
    f32x4 h00={0,0,0,0}, h01=h00, h10=h00, h11=h00;   // [mf][nf]
    short8 p0 = LB(0,0), p1 = LB(0,1);
    short8 q0 = LB(1,0), q1 = LB(1,1);
    #pragma unroll
    for(int ks=0; ks<8; ks++){
      short8 r0, r1;
      if(ks < 6){ r0 = LB(ks+2,0); r1 = LB(ks+2,1); }
      short8 a0 = AF(0,ks), a1 = AF(1,ks);
      h00 = MF(a0, p0, h00);
      h01 = MF(a0, p1, h01);
      h10 = MF(a1, p0, h10);
      h11 = MF(a1, p1, h11);
      p0 = q0; p1 = q1;
      if(ks < 6){ q0 = r0; q1 = r1; }
    }
    // epilogue -> wave-private transposed slice: one b64 per (mf,nf)
    #pragma unroll
    for(int mf=0;mf<2;mf++)
      #pragma unroll
      for(int nf=0;nf<2;nf++){
        f32x4 hv = mf==0 ? (nf==0?h00:h01) : (nf==0?h10:h11);
        short4a wv;
        wv[0] = (short)f2bf(hv[0]); wv[1] = (short)f2bf(hv[1]);
        wv[2] = (short)f2bf(hv[2]); wv[3] = (short)f2bf(hv[3]);
        *(short4a*)(myY + (nf*16+nlo)*72 + mf*32 + khi*8) = wv;
      }
    // mix chunk v+1 from own slice: two b64 per nf (contiguous c)
    {
      int wiA = nlo*224 + (v+1)*32 + khi*8;
      short8 wh0 = *(const short8*)(WH + wiA);
      short8 wl0 = *(const short8*)(WL + wiA);
      short8 wh1 = *(const short8*)(WH + wiA + 3584);
      short8 wl1 = *(const short8*)(WL + wiA + 3584);
      #pragma unroll
      for(int nf=0;nf<2;nf++){
        const char* rp = myY + (nf*16+nlo)*72 + khi*16;
        short4a flo = *(const short4a*)rp;
        short4a fhi = *(const short4a*)(rp + 8);
        short8 f = {flo[0],flo[1],flo[2],flo[3],fhi[0],fhi[1],fhi[2],fhi[3]};
        if(nf==0){ out00=MF(wh0,f,out00); out00=MF(wl0,f,out00); out10=MF(wh1,f,out10); out10=MF(wl1,f,out10); }
        else     { out01=MF(wh0,f,out01); out01=MF(wl0,f,out01); out11=MF(wh1,f,out11); out11=MF(wl1,f,out11); }
      }
    }
  }

  #pragma unroll
  for(int ot=0;ot<2;ot++)
    #pragma unroll
    for(int nf=0;nf<2;nf++)
      #pragma unroll
      for(int rr=0;rr<4;rr++){
        f32x4 ov = ot==0 ? (nf==0?out00:out01) : (nf==0?out10:out11);
        int o = ot*16 + khi*4 + rr;
        int n = (ch*8 + wave*2 + nf)*16 + nlo;
        float val = ov[rr] + bm[o];
        size_t a = cbase + (size_t)o*256 + n;
        if(MODE==0){
          u16 hh = f2bf(val);
          mbh[a] = hh;
          mbl[a] = f2bf(val - bf2f(hh));
        } else {
          m[a] = val;
        }
      }
}
#undef LB
#undef MF
#undef AF

// ---------------- m [b][t][o][n] f32 -> dst [b][o][n][t] f32
__global__ __launch_bounds__(256) void k_tip(const float* __restrict__ m, float* __restrict__ dst){
  int tile = blockIdx.x & 15; int slice = blockIdx.x >> 4;
  int b = slice >> 5, o = slice & 31;
  int tn0 = (tile & 3) * 64, tt0 = (tile >> 2) * 64;
  __shared__ float l[64][65];
  int cc = threadIdx.x & 63, r0 = threadIdx.x >> 6;
  #pragma unroll
  for(int k=0;k<16;k++){ int r = r0 + 4*k;
    l[r][cc] = m[(((size_t)b*256 + (tt0+r))*32 + o)*256 + tn0 + cc];
  }
  __syncthreads();
  #pragma unroll
  for(int k=0;k<16;k++){ int r = r0 + 4*k;
    dst[(((size_t)b*32 + o)*256 + (tn0+r))*256 + tt0 + cc] = l[cc][r];
  }
}

extern "C" void kernel_launch(void* const* d_in, const int* in_sizes, int n_in,
                              void* d_out, int out_size, void* d_ws, size_t ws_size,
                              hipStream_t stream){
  (void)in_sizes; (void)n_in; (void)out_size;
  const float* x    = (const float*)d_in[0];
  const float* nv1  = (const float*)d_in[1];
  const float* nv2  = (const float*)d_in[2];
  const float* sup0 = (const float*)d_in[3];
  const float* sup1 = (const float*)d_in[4];
  const float* wf1 = (const float*)d_in[5];  const float* bf1v = (const float*)d_in[6];
  const float* wg1 = (const float*)d_in[7];  const float* bg1v = (const float*)d_in[8];
  const float* wf2 = (const float*)d_in[9];  const float* bf2v = (const float*)d_in[10];
  const float* wg2 = (const float*)d_in[11]; const float* bg2v = (const float*)d_in[12];
  const float* wm1 = (const float*)d_in[13]; const float* bm1 = (const float*)d_in[14];
  const float* wm2 = (const float*)d_in[15]; const float* bm2 = (const float*)d_in[16];
  float* out = (float*)d_out;
  char* ws = (char*)d_ws;
  const size_t MB = (size_t)1 << 20;

  u16*  badj  = (u16*)ws;                    // 384 KB
  u16*  badj2 = (u16*)(ws + 393216);         // 384 KB
  float* adp  = (float*)(ws + 786432);       // 256 KB
  u16*  whi   = (u16*)(ws + 1048576);        // 28 KB
  u16*  wlo   = (u16*)(ws + 1077248);        // 28 KB
  u16*  wcp   = (u16*)(ws + 1105920);        // 32 KB
  u16*  bpack = (u16*)(ws + 1179648);        // 768 KB, ends < 2 MB

  int tier = (ws_size >= 100*MB) ? 0 : 1;
  u16* h   = (u16*)(ws + 2*MB);
  u16* mbh = (u16*)(ws + 18*MB);
  u16* mbl = (u16*)(ws + 34*MB);
  u16* xT;
  float *m, *tmp = nullptr;
  if(tier==0){
    m  = (float*)(ws + 50*MB);
    xT = (u16*)(ws + 82*MB);
  } else {
    xT = mbh;                 // xT dead before fuse<0> writes mbh
    m  = out;
    tmp = (float*)(ws + 2*MB);
  }

  k_adp<<<256,256,0,stream>>>(nv1, nv2, adp);
  k_badj<<<768,256,0,stream>>>(sup0, sup1, adp, badj);
  k_wprep<<<88,256,0,stream>>>(wm1, wm2, wf1, wg1, wf2, wg2, whi, wlo, wcp);
  k_asq<<<12,256,0,stream>>>(badj, sup0, sup1, adp, badj2);
  k_pack<<<192,256,0,stream>>>(badj, badj2, bpack);
  k_tin<<<2048,256,0,stream>>>(x, xT);

  // block 1
  k_cv<0><<<1024,256,0,stream>>>(xT, (const u16*)0, wcp, 0, 1, bf1v, bg1v, h);
  k_fuse<0><<<2048,256,0,stream>>>(h, bpack, whi, wlo, bm1, (float*)0, mbh, mbl);
  // block 2
  k_cv<1><<<1024,256,0,stream>>>(mbh, mbl, wcp, 1, 2, bf2v, bg2v, h);
  k_fuse<1><<<2048,256,0,stream>>>(h, bpack, whi+7168, wlo+7168, bm2, m, (u16*)0, (u16*)0);

  if(tier==0){
    k_tip<<<2048,256,0,stream>>>(m, out);
  } else {
    k_tip<<<2048,256,0,stream>>>(m, tmp);
    hipMemcpyAsync(out, tmp, (size_t)32*MB, hipMemcpyDeviceToDevice, stream);
  }
}

// Round 10
// 190.176 us; speedup vs baseline: 2.8016x; 1.0034x over previous
//
#include <hip/hip_runtime.h>
#include <hip/hip_bf16.h>
#include <stdint.h>

typedef unsigned short u16;
typedef __attribute__((ext_vector_type(8))) short short8;
typedef __attribute__((ext_vector_type(4))) short short4a;
typedef __attribute__((ext_vector_type(2))) unsigned int u32x2;
typedef __attribute__((ext_vector_type(4))) float f32x4;

__device__ __forceinline__ float bf2f(u16 b){ union {unsigned u; float f;} v; v.u = ((unsigned)b)<<16; return v.f; }
__device__ __forceinline__ u16 f2bf(float f){ union {unsigned u; float f;} v; v.f = f; unsigned r = v.u + 0x7FFF + ((v.u>>16)&1); return (u16)(r>>16); }

// ---------------- adaptive adjacency
__global__ __launch_bounds__(256) void k_adp(const float* __restrict__ nv1, const float* __restrict__ nv2,
                                             float* __restrict__ adp){
  int row = blockIdx.x; int j = threadIdx.x;
  float s = 0.f;
  #pragma unroll
  for(int k=0;k<10;k++) s = fmaf(nv1[row*10+k], nv2[k*256+j], s);
  s = s > 0.f ? s : 0.f;
  float val = (s == 0.f) ? -1e10f : s;
  __shared__ float red[256];
  red[j] = val; __syncthreads();
  for(int off=128; off>0; off>>=1){ if(j<off) red[j] = fmaxf(red[j], red[j+off]); __syncthreads(); }
  float mx = red[0]; __syncthreads();
  float e = __expf(val - mx);
  red[j] = e; __syncthreads();
  for(int off=128; off>0; off>>=1){ if(j<off) red[j] += red[j+off]; __syncthreads(); }
  adp[row*256+j] = e / red[0];
}

// ---------------- badj[s][w][v] = src_s[v][w]
__global__ __launch_bounds__(256) void k_badj(const float* __restrict__ s0, const float* __restrict__ s1,
                                              const float* __restrict__ adp, u16* __restrict__ badj){
  int s = blockIdx.x >> 8; int w = blockIdx.x & 255; int v = threadIdx.x;
  const float* src = s==0 ? s0 : (s==1 ? s1 : adp);
  badj[(s<<16) + (w<<8) + v] = f2bf(src[v*256 + w]);
}

// ---------------- weight prep
__global__ __launch_bounds__(256) void k_wprep(const float* __restrict__ wm1, const float* __restrict__ wm2,
                                               const float* __restrict__ wf1, const float* __restrict__ wg1,
                                               const float* __restrict__ wf2, const float* __restrict__ wg2,
                                               u16* __restrict__ whi, u16* __restrict__ wlo,
                                               u16* __restrict__ wcp){
  int idx = blockIdx.x*256 + threadIdx.x;
  if(idx < 14336){
    float w = (idx < 7168) ? wm1[idx] : wm2[idx-7168];
    u16 hh = f2bf(w);
    whi[idx] = hh;
    wlo[idx] = f2bf(w - bf2f(hh));
  } else {
    int e = idx - 14336;
    int blk = e >> 12; int rem = e & 4095;
    int row = rem >> 6; int kk = rem & 63;
    int tap = kk >> 5; int i = kk & 31; int o = row & 31;
    const float* wsrc = blk ? (row<32 ? wf2 : wg2) : (row<32 ? wf1 : wg1);
    float w = wsrc[(o*32+i)*2 + tap];
    u16 hh = f2bf(w);
    wcp[blk*8192 + 0    + rem] = hh;
    wcp[blk*8192 + 4096 + rem] = f2bf(w - bf2f(hh));
  }
}

// ---------------- x [b][c][n][t] f32 -> xT [b][t][c][n] bf16
__global__ __launch_bounds__(256) void k_tin(const float* __restrict__ x, u16* __restrict__ xT){
  int tile = blockIdx.x & 15; int slice = blockIdx.x >> 4;
  int b = slice >> 5, c = slice & 31;
  int tn0 = (tile & 3) * 64;
  int tt0 = (tile >> 2) * 64;
  const float* src = x + (size_t)slice*65536;
  __shared__ float l[64][65];
  int cc = threadIdx.x & 63, r0 = threadIdx.x >> 6;
  #pragma unroll
  for(int k=0;k<16;k++){ int r = r0 + 4*k;
    l[r][cc] = src[(size_t)(tn0 + r)*256 + tt0 + cc];
  }
  __syncthreads();
  #pragma unroll
  for(int k=0;k<16;k++){ int r = r0 + 4*k;
    xT[(((size_t)b*256 + (tt0+r))*32 + c)*256 + tn0 + cc] = f2bf(l[cc][r]);
  }
}

// ---------------- badj2[s] = badj[s] . badj[s]  (= (A^2)^T stored [w][v])
__global__ __launch_bounds__(256) void k_asq(const u16* __restrict__ badj,
                                             const float* __restrict__ s0, const float* __restrict__ s1,
                                             const float* __restrict__ adp, u16* __restrict__ badj2){
  __shared__ __align__(16) u16 lds[16384];
  int tid = threadIdx.x, bid = blockIdx.x;
  int s = bid >> 2, rt = bid & 3;
  int w0 = rt << 6;
  const u16* T = badj + (s<<16);
  const float* S = s==0 ? s0 : (s==1 ? s1 : adp);
  #pragma unroll
  for(int i=0;i<8;i++){
    int off = i*4096 + tid*16;
    int row = off >> 9;
    int P = (off >> 4) & 31;
    int L = (P & 16) | ((P & 15) ^ (row & 15));
    short8 v = *(const short8*)((const char*)T + (size_t)(w0 + row)*512 + L*16);
    *(short8*)((char*)lds + off) = v;
  }
  __syncthreads();
  int lane = tid & 63, wave = tid >> 6;
  int wr = (wave >> 1) << 5, wc = (wave & 1) << 7;
  f32x4 acc[2][8];
  #pragma unroll
  for(int a=0;a<2;a++)
    #pragma unroll
    for(int q=0;q<8;q++) acc[a][q] = {0.f,0.f,0.f,0.f};
  for(int ks=0; ks<8; ks++){
    short8 afr[2], bfr[8];
    #pragma unroll
    for(int mf=0; mf<2; mf++){
      int row = wr + mf*16 + (lane & 15);
      int L = ks*4 + (lane >> 4);
      int P = (L & 16) | ((L & 15) ^ (row & 15));
      afr[mf] = *(const short8*)&lds[row*256 + P*8];
    }
    #pragma unroll
    for(int nf=0; nf<8; nf++){
      int col = wc + nf*16 + (lane & 15);
      const float* src = S + (size_t)col*256 + ks*32 + (lane>>4)*8;
      #pragma unroll
      for(int jj=0;jj<8;jj++) bfr[nf][jj] = (short)f2bf(src[jj]);
    }
    #pragma unroll
    for(int mf=0;mf<2;mf++)
      #pragma unroll
      for(int nf=0;nf<8;nf++)
        acc[mf][nf] = __builtin_amdgcn_mfma_f32_16x16x32_bf16(afr[mf], bfr[nf], acc[mf][nf], 0,0,0);
  }
  u16* D = badj2 + (s<<16) + (size_t)w0*256;
  #pragma unroll
  for(int mf=0;mf<2;mf++)
    #pragma unroll
    for(int nf=0;nf<8;nf++)
      #pragma unroll
      for(int rr=0;rr<4;rr++){
        int row = wr + mf*16 + (lane>>4)*4 + rr;
        int col = wc + nf*16 + (lane&15);
        D[row*256 + col] = f2bf(acc[mf][nf][rr]);
      }
}

// ---------------- pack adjacency into MFMA B-fragment order (49152 threads -> grid 192)
__global__ __launch_bounds__(256) void k_pack(const u16* __restrict__ badj, const u16* __restrict__ badj2,
                                              u16* __restrict__ bpack){
  int t = blockIdx.x*256 + threadIdx.x;      // < 49152
  int lane = t & 63; int cg = (t>>6)&15; int ks = (t>>10)&7; int mat = (t>>13)&1; int s = t>>14;
  const u16* src = (mat ? badj2 : badj) + (s<<16) + (cg*16 + (lane&15))*256 + ks*32 + (lane>>4)*8;
  short8 v = *(const short8*)src;
  *(short8*)(bpack + (size_t)t*8) = v;
}

// ---------------- MFMA gated conv (+bias, sigmoid gate)
template<int HILO>
__global__ __launch_bounds__(256) void k_cv(const u16* __restrict__ X0, const u16* __restrict__ X1,
                                            const u16* __restrict__ wcp, int blk, int dil,
                                            const float* __restrict__ bfv, const float* __restrict__ bgv,
                                            u16* __restrict__ outh){
  __shared__ __align__(16) u16 pl[(1+HILO)*2*8192];
  const int NPART = 1+HILO;
  int tid = threadIdx.x, bid = blockIdx.x;
  int b = bid >> 8, t = bid & 255;
  size_t base_cur = ((size_t)(b*256 + t))*8192;
  const u16* Xs[2] = {X0, X1};
  #pragma unroll
  for(int part=0; part<NPART; part++){
    #pragma unroll
    for(int tap=0; tap<2; tap++){
      bool valid = (tap==1) || (t >= dil);
      const u16* src = Xs[part] + base_cur - (tap==0 ? (size_t)dil*8192 : 0);
      char* pb = (char*)pl + (tap*NPART + part)*16384;
      #pragma unroll
      for(int it=0; it<4; it++){
        int off = it*4096 + tid*16;
        int c = off >> 9;
        int byte = off & 511;
        short8 v = {0,0,0,0,0,0,0,0};
        if(valid) v = *(const short8*)(src + (off>>1));
        *(short8*)(pb + c*512 + (byte ^ ((c&24)<<2))) = v;
      }
    }
  }
  int lane = tid & 63, wave = tid >> 6;
  const u16* wb = wcp + blk*8192;
  short8 wfr[4][2][2];
  #pragma unroll
  for(int ot=0;ot<4;ot++)
    #pragma unroll
    for(int ks=0;ks<2;ks++)
      #pragma unroll
      for(int p=0;p<2;p++)
        wfr[ot][ks][p] = *(const short8*)(wb + p*4096 + (ot*16 + (lane&15))*64 + ks*32 + (lane>>4)*8);
  __syncthreads();

  f32x4 acc[4][4];
  #pragma unroll
  for(int a=0;a<4;a++)
    #pragma unroll
    for(int q=0;q<4;q++) acc[a][q] = {0.f,0.f,0.f,0.f};
  int nbase = wave << 6;
  #pragma unroll
  for(int nf=0; nf<4; nf++){
    int n = nbase + nf*16 + (lane & 15);
    #pragma unroll
    for(int ks=0; ks<2; ks++){
      short8 xv[NPART];
      #pragma unroll
      for(int p=0;p<NPART;p++){
        char* pb = (char*)pl + (ks*NPART + p)*16384;
        short8 v;
        #pragma unroll
        for(int jj=0;jj<8;jj++){
          int c = ((lane>>4)<<3) + jj;
          v[jj] = *(const short*)(pb + c*512 + ((n*2) ^ ((c&24)<<2)));
        }
        xv[p] = v;
      }
      #pragma unroll
      for(int ot=0; ot<4; ot++){
        acc[ot][nf] = __builtin_amdgcn_mfma_f32_16x16x32_bf16(wfr[ot][ks][0], xv[0], acc[ot][nf], 0,0,0);
        acc[ot][nf] = __builtin_amdgcn_mfma_f32_16x16x32_bf16(wfr[ot][ks][1], xv[0], acc[ot][nf], 0,0,0);
        if(HILO)
          acc[ot][nf] = __builtin_amdgcn_mfma_f32_16x16x32_bf16(wfr[ot][ks][0], xv[HILO], acc[ot][nf], 0,0,0);
      }
    }
  }
  u16* ob = outh + base_cur;
  #pragma unroll
  for(int ot=0; ot<2; ot++)
    #pragma unroll
    for(int nf=0; nf<4; nf++)
      #pragma unroll
      for(int rr=0; rr<4; rr++){
        int o = ot*16 + (lane>>4)*4 + rr;
        int n = nbase + nf*16 + (lane&15);
        float fv = acc[ot][nf][rr] + bfv[o];
        float gv = acc[ot+2][nf][rr] + bgv[o];
        ob[(size_t)o*256 + n] = f2bf(fv / (1.f + __expf(-gv)));
      }
}

// ---------------- fused hop+mix v4: flat 48-step pipeline, depth-3 rolling B prefetch
// crossing support boundaries; setprio around MFMA clusters; cvt_pk epilogue.
// lA: h tile [32 c][256 v], row-XOR slot swizzle. lYT: per-wave [32 n][72 B] transposed slice.
#define LBF(V,KS,FC) (*(const short8*)(bpack + ((size_t)(V)<<16) + ((((KS)*16) + cg0 + (FC))<<9) + (lane<<3)))
#define MF(A,B,C) __builtin_amdgcn_mfma_f32_16x16x32_bf16((A),(B),(C),0,0,0)
#define AF(MFI,KS) (*(const short8*)&lA[(MFI*16 + nlo)*256 + (((KS*4+khi)&16)|(((KS*4+khi)&15)^((MFI*16+nlo)&15)))*8])
template<int MODE>
__global__ __launch_bounds__(256, 4) void k_fuse(const u16* __restrict__ X,
                                                 const u16* __restrict__ bpack,
                                                 const u16* __restrict__ WH, const u16* __restrict__ WL,
                                                 const float* __restrict__ bm,
                                                 float* __restrict__ m, u16* __restrict__ mbh, u16* __restrict__ mbl){
  __shared__ __align__(16) u16 lA[8192];     // 16 KB
  __shared__ __align__(16) char lYT[9216];   // 4 waves x 32 n x 72 B
  int tid = threadIdx.x, bid = blockIdx.x;
  int ch = bid & 1;
  size_t cbase = (size_t)(bid >> 1) * 8192;
  const char* Xb = (const char*)(X + cbase);
  #pragma unroll
  for(int i=0;i<4;i++){
    int off = i*4096 + tid*16;
    int row = off >> 9;
    int P = (off >> 4) & 31;
    int L = (P & 16) | ((P & 15) ^ (row & 15));
    short8 v = *(const short8*)(Xb + (size_t)row*512 + L*16);
    *(short8*)((char*)lA + off) = v;
  }
  __syncthreads();
  int lane = tid & 63, wave = tid >> 6;
  int nlo = lane & 15, khi = lane >> 4;
  int cg0 = ch*8 + wave*2;
  char* myY = lYT + wave*2304;

  f32x4 out00={0,0,0,0}, out01=out00, out10=out00, out11=out00;

  // rolling depth-3 prefetch: steps 0,1,2
  short8 pA = LBF(0,0,0), pB = LBF(0,0,1);
  short8 qA = LBF(0,1,0), qB = LBF(0,1,1);
  short8 rA = LBF(0,2,0), rB = LBF(0,2,1);

  // mix chunk 0 (= h itself) from lA (scalar gather, once per block) — covers initial load latency
  {
    int wiA = nlo*224 + khi*8;
    short8 wh0 = *(const short8*)(WH + wiA);
    short8 wl0 = *(const short8*)(WL + wiA);
    short8 wh1 = *(const short8*)(WH + wiA + 3584);
    short8 wl1 = *(const short8*)(WL + wiA + 3584);
    #pragma unroll
    for(int nf=0;nf<2;nf++){
      int n = (ch*8 + wave*2 + nf)*16 + nlo;
      short8 f; int Lc = n >> 3; int bb = (n & 7)*2;
      #pragma unroll
      for(int j=0;j<8;j++){
        int c = khi*8 + j;
        int P = (Lc & 16) | ((Lc & 15) ^ (c & 15));
        f[j] = *(const u16*)((const char*)lA + c*512 + P*16 + bb);
      }
      if(nf==0){ out00=MF(wh0,f,out00); out00=MF(wl0,f,out00); out10=MF(wh1,f,out10); out10=MF(wl1,f,out10); }
      else     { out01=MF(wh0,f,out01); out01=MF(wl0,f,out01); out11=MF(wh1,f,out11); out11=MF(wl1,f,out11); }
    }
  }

  #pragma unroll
  for(int v=0; v<6; v++){
    f32x4 h00={0,0,0,0}, h01=h00, h10=h00, h11=h00;
    #pragma unroll
    for(int ks=0; ks<8; ks++){
      const int step = v*8 + ks;
      short8 a0 = AF(0,ks), a1 = AF(1,ks);
      __builtin_amdgcn_s_setprio(1);
      if(step%3==0){
        h00=MF(a0,pA,h00); h01=MF(a0,pB,h01); h10=MF(a1,pA,h10); h11=MF(a1,pB,h11);
      } else if(step%3==1){
        h00=MF(a0,qA,h00); h01=MF(a0,qB,h01); h10=MF(a1,qA,h10); h11=MF(a1,qB,h11);
      } else {
        h00=MF(a0,rA,h00); h01=MF(a0,rB,h01); h10=MF(a1,rA,h10); h11=MF(a1,rB,h11);
      }
      __builtin_amdgcn_s_setprio(0);
      if(step+3 < 48){
        const int s2 = step+3, V2 = s2>>3, K2 = s2&7;
        if(step%3==0){ pA = LBF(V2,K2,0); pB = LBF(V2,K2,1); }
        else if(step%3==1){ qA = LBF(V2,K2,0); qB = LBF(V2,K2,1); }
        else { rA = LBF(V2,K2,0); rB = LBF(V2,K2,1); }
      }
    }
    // epilogue -> wave-private transposed slice: cvt_pk pairs + one b64 per (mf,nf)
    #pragma unroll
    for(int mf=0;mf<2;mf++)
      #pragma unroll
      for(int nf=0;nf<2;nf++){
        f32x4 hv = mf==0 ? (nf==0?h00:h01) : (nf==0?h10:h11);
        u32x2 wv;
        asm("v_cvt_pk_bf16_f32 %0, %1, %2" : "=v"(wv[0]) : "v"(hv[0]), "v"(hv[1]));
        asm("v_cvt_pk_bf16_f32 %0, %1, %2" : "=v"(wv[1]) : "v"(hv[2]), "v"(hv[3]));
        *(u32x2*)(myY + (nf*16+nlo)*72 + mf*32 + khi*8) = wv;
      }
    // mix chunk v+1 from own slice: two b64 per nf (contiguous c)
    {
      int wiA = nlo*224 + (v+1)*32 + khi*8;
      short8 wh0 = *(const short8*)(WH + wiA);
      short8 wl0 = *(const short8*)(WL + wiA);
      short8 wh1 = *(const short8*)(WH + wiA + 3584);
      short8 wl1 = *(const short8*)(WL + wiA + 3584);
      __builtin_amdgcn_s_setprio(1);
      #pragma unroll
      for(int nf=0;nf<2;nf++){
        const char* rp = myY + (nf*16+nlo)*72 + khi*16;
        short4a flo = *(const short4a*)rp;
        short4a fhi = *(const short4a*)(rp + 8);
        short8 f = {flo[0],flo[1],flo[2],flo[3],fhi[0],fhi[1],fhi[2],fhi[3]};
        if(nf==0){ out00=MF(wh0,f,out00); out00=MF(wl0,f,out00); out10=MF(wh1,f,out10); out10=MF(wl1,f,out10); }
        else     { out01=MF(wh0,f,out01); out01=MF(wl0,f,out01); out11=MF(wh1,f,out11); out11=MF(wl1,f,out11); }
      }
      __builtin_amdgcn_s_setprio(0);
    }
  }

  #pragma unroll
  for(int ot=0;ot<2;ot++)
    #pragma unroll
    for(int nf=0;nf<2;nf++)
      #pragma unroll
      for(int rr=0;rr<4;rr++){
        f32x4 ov = ot==0 ? (nf==0?out00:out01) : (nf==0?out10:out11);
        int o = ot*16 + khi*4 + rr;
        int n = (ch*8 + wave*2 + nf)*16 + nlo;
        float val = ov[rr] + bm[o];
        size_t a = cbase + (size_t)o*256 + n;
        if(MODE==0){
          u16 hh = f2bf(val);
          mbh[a] = hh;
          mbl[a] = f2bf(val - bf2f(hh));
        } else {
          m[a] = val;
        }
      }
}
#undef LBF
#undef MF
#undef AF

// ---------------- m [b][t][o][n] f32 -> dst [b][o][n][t] f32
__global__ __launch_bounds__(256) void k_tip(const float* __restrict__ m, float* __restrict__ dst){
  int tile = blockIdx.x & 15; int slice = blockIdx.x >> 4;
  int b = slice >> 5, o = slice & 31;
  int tn0 = (tile & 3) * 64, tt0 = (tile >> 2) * 64;
  __shared__ float l[64][65];
  int cc = threadIdx.x & 63, r0 = threadIdx.x >> 6;
  #pragma unroll
  for(int k=0;k<16;k++){ int r = r0 + 4*k;
    l[r][cc] = m[(((size_t)b*256 + (tt0+r))*32 + o)*256 + tn0 + cc];
  }
  __syncthreads();
  #pragma unroll
  for(int k=0;k<16;k++){ int r = r0 + 4*k;
    dst[(((size_t)b*32 + o)*256 + (tn0+r))*256 + tt0 + cc] = l[cc][r];
  }
}

extern "C" void kernel_launch(void* const* d_in, const int* in_sizes, int n_in,
                              void* d_out, int out_size, void* d_ws, size_t ws_size,
                              hipStream_t stream){
  (void)in_sizes; (void)n_in; (void)out_size;
  const float* x    = (const float*)d_in[0];
  const float* nv1  = (const float*)d_in[1];
  const float* nv2  = (const float*)d_in[2];
  const float* sup0 = (const float*)d_in[3];
  const float* sup1 = (const float*)d_in[4];
  const float* wf1 = (const float*)d_in[5];  const float* bf1v = (const float*)d_in[6];
  const float* wg1 = (const float*)d_in[7];  const float* bg1v = (const float*)d_in[8];
  const float* wf2 = (const float*)d_in[9];  const float* bf2v = (const float*)d_in[10];
  const float* wg2 = (const float*)d_in[11]; const float* bg2v = (const float*)d_in[12];
  const float* wm1 = (const float*)d_in[13]; const float* bm1 = (const float*)d_in[14];
  const float* wm2 = (const float*)d_in[15]; const float* bm2 = (const float*)d_in[16];
  float* out = (float*)d_out;
  char* ws = (char*)d_ws;
  const size_t MB = (size_t)1 << 20;

  u16*  badj  = (u16*)ws;                    // 384 KB
  u16*  badj2 = (u16*)(ws + 393216);         // 384 KB
  float* adp  = (float*)(ws + 786432);       // 256 KB
  u16*  whi   = (u16*)(ws + 1048576);        // 28 KB
  u16*  wlo   = (u16*)(ws + 1077248);        // 28 KB
  u16*  wcp   = (u16*)(ws + 1105920);        // 32 KB
  u16*  bpack = (u16*)(ws + 1179648);        // 768 KB, ends < 2 MB

  int tier = (ws_size >= 100*MB) ? 0 : 1;
  u16* h   = (u16*)(ws + 2*MB);
  u16* mbh = (u16*)(ws + 18*MB);
  u16* mbl = (u16*)(ws + 34*MB);
  u16* xT;
  float *m, *tmp = nullptr;
  if(tier==0){
    m  = (float*)(ws + 50*MB);
    xT = (u16*)(ws + 82*MB);
  } else {
    xT = mbh;                 // xT dead before fuse<0> writes mbh
    m  = out;
    tmp = (float*)(ws + 2*MB);
  }

  k_adp<<<256,256,0,stream>>>(nv1, nv2, adp);
  k_badj<<<768,256,0,stream>>>(sup0, sup1, adp, badj);
  k_wprep<<<88,256,0,stream>>>(wm1, wm2, wf1, wg1, wf2, wg2, whi, wlo, wcp);
  k_asq<<<12,256,0,stream>>>(badj, sup0, sup1, adp, badj2);
  k_pack<<<192,256,0,stream>>>(badj, badj2, bpack);
  k_tin<<<2048,256,0,stream>>>(x, xT);

  // block 1
  k_cv<0><<<1024,256,0,stream>>>(xT, (const u16*)0, wcp, 0, 1, bf1v, bg1v, h);
  k_fuse<0><<<2048,256,0,stream>>>(h, bpack, whi, wlo, bm1, (float*)0, mbh, mbl);
  // block 2
  k_cv<1><<<1024,256,0,stream>>>(mbh, mbl, wcp, 1, 2, bf2v, bg2v, h);
  k_fuse<1><<<2048,256,0,stream>>>(h, bpack, whi+7168, wlo+7168, bm2, m, (u16*)0, (u16*)0);

  if(tier==0){
    k_tip<<<2048,256,0,stream>>>(m, out);
  } else {
    k_tip<<<2048,256,0,stream>>>(m, tmp);
    hipMemcpyAsync(out, tmp, (size_t)32*MB, hipMemcpyDeviceToDevice, stream);
  }
}